// Round 1
// baseline (2699.454 us; speedup 1.0000x reference)
//
#include <hip/hip_runtime.h>
#include <stdint.h>

#define HWDIM 224
#define NPIX (HWDIM*HWDIM)
#define NFIELD 12
#define TT 25

#define R1v 37
#define PW1v (HWDIM + 2*R1v)        /* 298 */
#define PN1v (PW1v*PW1v)            /* 88804 */
#define NB1v (2*R1v*R1v + 1)        /* 2739 */
#define NOFF1v ((2*R1v+1)*(2*R1v+1))/* 5625 */
#define NOFF1P 5632

#define R2v 74
#define PW2v (HWDIM + 2*R2v)        /* 372 */
#define PN2v (PW2v*PW2v)            /* 138384 */
#define NB2v (2*R2v*R2v + 1)        /* 10953 */
#define NOFF2v ((2*R2v+1)*(2*R2v+1))/* 22201 */
#define NOFF2P 22208

#define HSIZE 65536
#define FCAP2 4096
#define PCAP 4160

struct LayerParams {
    const float* tseq[6];
    const float* gw[6];
    const float* gb[6];
};

// ---------------- workspace layout ----------------
constexpr size_t alup(size_t x) { return (x + 255) & ~(size_t)255; }
constexpr size_t OFF_SUMS = 0;
constexpr size_t OFF_HIST = alup(OFF_SUMS + 8*4);
constexpr size_t OFF_TAB1 = alup(OFF_HIST + (size_t)2*16384*4);
constexpr size_t OFF_TAB2 = alup(OFF_TAB1 + (size_t)NOFF1P*8);
constexpr size_t OFF_PAD1 = alup(OFF_TAB2 + (size_t)NOFF2P*8);
constexpr size_t OFF_PAD2 = alup(OFF_PAD1 + (size_t)6*PN1v*4);
constexpr size_t OFF_DT   = alup(OFF_PAD2 + (size_t)6*PN2v*4);
constexpr size_t OFF_KEY  = alup(OFF_DT   + (size_t)NFIELD*NPIX*4);
constexpr size_t OFF_ROOT = alup(OFF_KEY  + (size_t)NFIELD*NPIX*8);
constexpr size_t OFF_COMP = alup(OFF_ROOT + (size_t)NFIELD*NPIX*4);
constexpr size_t OFF_HP   = alup(OFF_COMP + (size_t)NFIELD*NPIX*4);
constexpr size_t OFF_HB   = alup(OFF_HP   + (size_t)NFIELD*HSIZE*8);
constexpr size_t OFF_PY   = alup(OFF_HB   + (size_t)NFIELD*HSIZE*8);
constexpr size_t OFF_PD   = alup(OFF_PY   + (size_t)NFIELD*PCAP*4);
constexpr size_t OFF_PP   = alup(OFF_PD   + (size_t)NFIELD*PCAP*4);
constexpr size_t OFF_SEL  = alup(OFF_PP   + (size_t)NFIELD*PCAP*4);
constexpr size_t OFF_X    = alup(OFF_SEL  + (size_t)NFIELD*64*16);

// ---------------- kernels ----------------

__global__ __launch_bounds__(256) void k_sums(const float* __restrict__ inp, float* __restrict__ sums) {
    int img = blockIdx.x; // 0..5 = b*3+c
    const float* p = inp + (size_t)img * NPIX;
    __shared__ float red[256];
    float s = 0.f;
    for (int i = threadIdx.x; i < NPIX; i += 256) s += p[i];
    red[threadIdx.x] = s; __syncthreads();
    for (int w = 128; w > 0; w >>= 1) {
        if (threadIdx.x < w) red[threadIdx.x] += red[threadIdx.x + w];
        __syncthreads();
    }
    if (threadIdx.x == 0) sums[img] = red[0];
}

__global__ __launch_bounds__(1024) void k_offsets(int* __restrict__ hist, int2* __restrict__ tab1, int2* __restrict__ tab2) {
    int g = blockIdx.x;
    const int R = g ? R2v : R1v;
    const int PW = g ? PW2v : PW1v;
    const int NB = g ? NB2v : NB1v;
    const int NOFF = g ? NOFF2v : NOFF1v;
    const int NOFFP = g ? NOFF2P : NOFF1P;
    int2* tab = g ? tab2 : tab1;
    int* h = hist + g * 16384;
    const int tid = threadIdx.x, bs = 1024;
    for (int i = tid; i < NB; i += bs) h[i] = 0;
    __syncthreads();
    const int S = 2*R + 1;
    for (int i = tid; i < NOFF; i += bs) {
        int dy = i / S - R, dx = i % S - R;
        atomicAdd(&h[dy*dy + dx*dx], 1);
    }
    __syncthreads();
    // chunked exclusive scan of h[0..NB)
    __shared__ int part[2][1024];
    const int chunk = (NB + bs - 1) / bs;
    int lo = tid * chunk, hi = lo + chunk; if (hi > NB) hi = NB; if (lo > NB) lo = NB;
    int mysum = 0;
    for (int i = lo; i < hi; ++i) mysum += h[i];
    int cur = 0;
    part[0][tid] = mysum; __syncthreads();
    for (int off = 1; off < bs; off <<= 1) {
        int v = part[cur][tid];
        if (tid >= off) v += part[cur][tid - off];
        part[cur ^ 1][tid] = v;
        __syncthreads();
        cur ^= 1;
    }
    int base = part[cur][tid] - mysum; // exclusive prefix of my chunk
    int run = base;
    for (int i = lo; i < hi; ++i) { int c = h[i]; h[i] = run; run += c; }
    __syncthreads();
    // scatter (order within equal-d2 bin is irrelevant for the DTM sum)
    for (int i = tid; i < NOFF; i += bs) {
        int dy = i / S - R, dx = i % S - R;
        int d2 = dy*dy + dx*dx;
        int pos = atomicAdd(&h[d2], 1);
        int2 e; e.x = dy*PW + dx; e.y = __float_as_int((float)d2);
        tab[pos] = e;
    }
    for (int i = NOFF + tid; i < NOFFP; i += bs) { int2 e; e.x = 0; e.y = 0; tab[i] = e; }
}

__global__ __launch_bounds__(256) void k_pad(const float* __restrict__ inp, float* __restrict__ pad1, float* __restrict__ pad2) {
    int i = blockIdx.x * 256 + threadIdx.x;
    const int tot1 = 6 * PN1v;
    const int tot = tot1 + 6 * PN2v;
    if (i >= tot) return;
    int g = (i >= tot1);
    int rem = g ? (i - tot1) : i;
    const int PN = g ? PN2v : PN1v, PW = g ? PW2v : PW1v, R = g ? R2v : R1v;
    int img = rem / PN, e = rem % PN;
    int py = e / PW, px = e % PW;
    int iy = py - R, ix = px - R;
    float v = 0.f;
    if ((unsigned)iy < HWDIM && (unsigned)ix < HWDIM) v = inp[(size_t)img*NPIX + iy*HWDIM + ix];
    (g ? pad2 : pad1)[(size_t)img*PN + e] = v;
}

__global__ __launch_bounds__(256) void k_init(unsigned long long* __restrict__ hp, unsigned long long* __restrict__ hb) {
    size_t i = (size_t)blockIdx.x * 256 + threadIdx.x;
    if (i < (size_t)NFIELD * HSIZE) { hp[i] = ~0ull; hb[i] = ~0ull; }
}

__global__ __launch_bounds__(256) void k_dtm(const float* __restrict__ sums,
        const int2* __restrict__ tab1, const int2* __restrict__ tab2,
        const float* __restrict__ pad1, const float* __restrict__ pad2,
        float* __restrict__ dt, unsigned long long* __restrict__ key) {
    const int f = blockIdx.y;            // field = layer*2 + b
    const int layer = f >> 1, b = f & 1;
    const int g = layer / 3, c = layer % 3;
    const int img = b*3 + c;
    const int p = blockIdx.x * 256 + threadIdx.x;
    const int2* __restrict__ tab = g ? tab2 : tab1;
    const float* __restrict__ pad = (g ? pad2 : pad1) + (size_t)img * (g ? PN2v : PN1v);
    const int R = g ? R2v : R1v, PW = g ? PW2v : PW1v, NOFFP = g ? NOFF2P : NOFF1P;
    const float m0 = g ? 0.2f : 0.05f;
    const float thr = m0 * sums[img];
    const int y = p / HWDIM, x = p % HWDIM;
    const float* base = pad + (y + R) * PW + (x + R);
    float cacc = 0.f, s = 0.f;
    for (int j = 0; j < NOFFP; j += 16) {
        #pragma unroll
        for (int u = 0; u < 16; ++u) {
            int2 od = tab[j + u];
            float w = base[od.x];
            float used = fminf(fmaxf(thr - cacc, 0.f), w);
            s = fmaf(used, __int_as_float(od.y), s);
            cacc += w;
        }
        if (__all(cacc >= thr)) break;
    }
    float d = sqrtf(fmaxf(s / thr, 0.f));
    dt[(size_t)f*NPIX + p] = d;
    key[(size_t)f*NPIX + p] = ((unsigned long long)__float_as_uint(d) << 32) | (unsigned)p;
}

__global__ __launch_bounds__(256) void k_descent(const unsigned long long* __restrict__ key, int* __restrict__ rootd) {
    const int f = blockIdx.y;
    const int p = blockIdx.x * 256 + threadIdx.x;
    const unsigned long long* k = key + (size_t)f*NPIX;
    unsigned long long best = k[p]; int bi = p;
    const int y = p / HWDIM, x = p % HWDIM;
    if (y > 0)        { unsigned long long t = k[p - HWDIM]; if (t < best) { best = t; bi = p - HWDIM; } }
    if (y < HWDIM-1)  { unsigned long long t = k[p + HWDIM]; if (t < best) { best = t; bi = p + HWDIM; } }
    if (x > 0)        { unsigned long long t = k[p - 1];     if (t < best) { best = t; bi = p - 1; } }
    if (x < HWDIM-1)  { unsigned long long t = k[p + 1];     if (t < best) { best = t; bi = p + 1; } }
    rootd[(size_t)f*NPIX + p] = bi;
}

__global__ __launch_bounds__(1024) void k_jump(int* __restrict__ rootd) {
    int* r = rootd + (size_t)blockIdx.x * NPIX;
    for (int pass = 0; pass < 18; ++pass) {
        for (int p = threadIdx.x; p < NPIX; p += 1024) r[p] = r[r[p]];
        __syncthreads();
    }
}

__device__ inline unsigned hash64(unsigned long long x) {
    x ^= x >> 33; x *= 0xff51afd7ed558ccdULL;
    x ^= x >> 33; x *= 0xc4ceb9fe1a85ec53ULL;
    x ^= x >> 33;
    return (unsigned)x;
}

__global__ __launch_bounds__(256) void k_edges(const unsigned long long* __restrict__ key, const int* __restrict__ rootd,
        unsigned long long* __restrict__ hpair, unsigned long long* __restrict__ hbest) {
    const int f = blockIdx.y;
    const int p = blockIdx.x * 256 + threadIdx.x;
    const unsigned long long* k = key + (size_t)f*NPIX;
    const int* r = rootd + (size_t)f*NPIX;
    unsigned long long* hp = hpair + (size_t)f*HSIZE;
    unsigned long long* hb = hbest + (size_t)f*HSIZE;
    const int y = p / HWDIM, x = p % HWDIM;
    const int rp = r[p];
    const unsigned long long kp = k[p];
    #pragma unroll
    for (int e = 0; e < 2; ++e) {
        int q;
        if (e == 0) { if (x >= HWDIM-1) continue; q = p + 1; }
        else        { if (y >= HWDIM-1) continue; q = p + HWDIM; }
        int rq = r[q];
        if (rq == rp) continue;
        unsigned long long kq = k[q];
        unsigned long long ek = (kp > kq) ? kp : kq;      // key of death (later) endpoint
        int ra = min(rp, rq), rb = max(rp, rq);
        unsigned long long pk = ((unsigned long long)(unsigned)ra << 32) | (unsigned)rb;
        unsigned h = hash64(pk) & (HSIZE - 1);
        for (int probe = 0; probe < HSIZE; ++probe) {
            unsigned long long old = atomicCAS(&hp[h], ~0ull, pk);
            if (old == ~0ull || old == pk) { atomicMin(&hb[h], ek); break; }
            h = (h + 1) & (HSIZE - 1);
        }
    }
}

__global__ __launch_bounds__(512) void k_finish(const float* __restrict__ dt, const unsigned long long* __restrict__ key,
        const int* __restrict__ rootd, int* __restrict__ comp,
        const unsigned long long* __restrict__ hpair, const unsigned long long* __restrict__ hbest,
        int* __restrict__ py, int* __restrict__ pd, float* __restrict__ pp, int4* __restrict__ sel) {
    const int f = blockIdx.x;
    const int tid = threadIdx.x; const int bs = 512;
    const float* dtf = dt + (size_t)f*NPIX;
    const unsigned long long* kf = key + (size_t)f*NPIX;
    const int* rf = rootd + (size_t)f*NPIX;
    int* cf = comp + (size_t)f*NPIX;
    const unsigned long long* hp = hpair + (size_t)f*HSIZE;
    const unsigned long long* hb = hbest + (size_t)f*HSIZE;
    int* fpy = py + f*PCAP; int* fpd = pd + f*PCAP; float* fpp = pp + f*PCAP;

    __shared__ unsigned long long ek[FCAP2];
    __shared__ int esl[FCAP2];
    __shared__ unsigned long long redk[512];
    __shared__ float redf[512];
    __shared__ int redi[512];
    __shared__ int cnt_s, pc_s;
    __shared__ int gmin_s, gmax_s; __shared__ float gminf_s, gmaxf_s;

    // comp init + global min/max reduce
    unsigned long long mymin = ~0ull;
    float bf = -1.f; int bi = 0x7fffffff;
    for (int p = tid; p < NPIX; p += bs) {
        cf[p] = rf[p];
        unsigned long long kk = kf[p];
        if (kk < mymin) mymin = kk;
        float v = __uint_as_float((unsigned)(kk >> 32));
        if (v > bf || (v == bf && p < bi)) { bf = v; bi = p; }
    }
    redk[tid] = mymin; redf[tid] = bf; redi[tid] = bi;
    __syncthreads();
    for (int w = bs/2; w > 0; w >>= 1) {
        if (tid < w) {
            if (redk[tid + w] < redk[tid]) redk[tid] = redk[tid + w];
            float vf = redf[tid + w]; int vi = redi[tid + w];
            if (vf > redf[tid] || (vf == redf[tid] && vi < redi[tid])) { redf[tid] = vf; redi[tid] = vi; }
        }
        __syncthreads();
    }
    if (tid == 0) {
        gmin_s = (int)(unsigned)redk[0];
        gminf_s = __uint_as_float((unsigned)(redk[0] >> 32));
        gmax_s = redi[0]; gmaxf_s = redf[0];
        cnt_s = 0; pc_s = 0;
    }
    __syncthreads();
    // compact hash table
    for (int i = tid; i < HSIZE; i += bs) {
        if (hp[i] != ~0ull) {
            int slot = atomicAdd(&cnt_s, 1);
            if (slot < FCAP2) { ek[slot] = hb[i]; esl[slot] = i; }
        }
    }
    __syncthreads();
    int cnt = cnt_s; if (cnt > FCAP2) cnt = FCAP2;
    for (int i = cnt + tid; i < FCAP2; i += bs) ek[i] = ~0ull;
    __syncthreads();
    // bitonic sort (ascending by ek)
    for (int k = 2; k <= FCAP2; k <<= 1) {
        for (int j = k >> 1; j > 0; j >>= 1) {
            for (int i = tid; i < FCAP2; i += bs) {
                int ixj = i ^ j;
                if (ixj > i) {
                    unsigned long long a = ek[i], b2 = ek[ixj];
                    bool up = ((i & k) == 0);
                    if (up ? (a > b2) : (a < b2)) {
                        ek[i] = b2; ek[ixj] = a;
                        int t2 = esl[i]; esl[i] = esl[ixj]; esl[ixj] = t2;
                    }
                }
            }
            __syncthreads();
        }
    }
    // sequential Kruskal (elder rule) on thread 0
    if (tid == 0) {
        int pc = 0;
        for (int i = 0; i < cnt; ++i) {
            unsigned long long ekey = ek[i];
            unsigned long long pk = hp[esl[i]];
            int ra = (int)(unsigned)(pk >> 32), rb = (int)(unsigned)pk;
            int u = (int)(unsigned)ekey;
            int ru0 = rf[u];
            int rv0 = (ru0 == ra) ? rb : ra;
            int a = ru0; while (cf[a] != a) { int g2 = cf[cf[a]]; cf[a] = g2; a = g2; }
            int b2 = rv0; while (cf[b2] != b2) { int g2 = cf[cf[b2]]; cf[b2] = g2; b2 = g2; }
            if (a != b2) {
                float fa = dtf[a], fb = dtf[b2];
                int elder, young;
                if (fa <= fb) { elder = a; young = b2; } else { elder = b2; young = a; }
                cf[young] = elder;
                float pers = __uint_as_float((unsigned)(ekey >> 32)) - dtf[young];
                if (pers > 0.f && pc < PCAP - 1) { fpy[pc] = young; fpd[pc] = u; fpp[pc] = pers; ++pc; }
            }
        }
        // global (argmin, argmax) pair
        fpy[pc] = gmin_s; fpd[pc] = gmax_s; fpp[pc] = gmaxf_s - gminf_s; ++pc;
        pc_s = pc;
    }
    __syncthreads();
    const int pc = pc_s;
    // top-64 by persistence (desc), deterministic tie-break by index
    for (int slot = 0; slot < 64; ++slot) {
        float bp = 0.f; int bidx = 0x7fffffff;
        for (int i = tid; i < pc; i += bs) {
            float v = fpp[i];
            if (v > 0.f && (v > bp || (v == bp && i < bidx))) { bp = v; bidx = i; }
        }
        redf[tid] = bp; redi[tid] = bidx;
        __syncthreads();
        for (int w = bs/2; w > 0; w >>= 1) {
            if (tid < w) {
                float vf = redf[tid + w]; int vi = redi[tid + w];
                if (vf > redf[tid] || (vf == redf[tid] && vi < redi[tid])) { redf[tid] = vf; redi[tid] = vi; }
            }
            __syncthreads();
        }
        if (tid == 0) {
            int4 o;
            if (redf[0] > 0.f) {
                int wdx = redi[0];
                o.x = fpy[wdx]; o.y = fpd[wdx]; o.z = 1; o.w = 0;
                fpp[wdx] = -1.f;
            } else { o.x = 0; o.y = 0; o.z = 0; o.w = 0; }
            sel[f*64 + slot] = o;
        }
        __syncthreads();
    }
}

__global__ __launch_bounds__(64) void k_feat(const float* __restrict__ dt, const int4* __restrict__ sel,
        LayerParams lp, float* __restrict__ x) {
    const int f = blockIdx.x; const int layer = f >> 1, b = f & 1;
    const float* dtf = dt + (size_t)f*NPIX;
    __shared__ float birth[64], death[64], feat[2*TT];
    const int tid = threadIdx.x;
    int4 s = sel[f*64 + tid];
    float bv = dtf[s.x];
    float dv = s.z ? dtf[s.y] : bv;
    birth[tid] = bv; death[tid] = dv;
    __syncthreads();
    if (tid < TT) {
        float t = lp.tseq[layer][tid];
        float m1 = 0.f, m2 = 0.f;
        for (int m = 0; m < 64; ++m) {
            float v = fmaxf(fminf(t - birth[m], death[m] - t), 0.f);
            if (v > m1) { m2 = m1; m1 = v; } else if (v > m2) m2 = v;
        }
        feat[tid] = m1; feat[TT + tid] = m2;
    }
    __syncthreads();
    if (tid < 50) {
        const float* w = lp.gw[layer] + tid * 50;
        float acc = lp.gb[layer][tid];
        #pragma unroll
        for (int j = 0; j < 50; ++j) acc = fmaf(feat[j], w[j], acc);
        x[b*300 + layer*50 + tid] = acc;
    }
}

__global__ __launch_bounds__(512) void k_final(const float* __restrict__ x, const float* __restrict__ fcw,
        const float* __restrict__ fcb, float* __restrict__ out) {
    __shared__ float rl[2][300];
    const int tid = threadIdx.x;
    if (tid < 300) {
        float a0 = x[tid], a1 = x[300 + tid];
        out[14 + tid] = fabsf(a0) + fabsf(a1);
        rl[0][tid] = fmaxf(a0, 0.f);
        rl[1][tid] = fmaxf(a1, 0.f);
    }
    __syncthreads();
    if (tid < 14) {
        int b = tid / 7, i = tid % 7;
        float acc = fcb[i];
        const float* w = fcw + i * 300;
        for (int j = 0; j < 300; ++j) acc = fmaf(rl[b][j], w[j], acc);
        out[b*7 + i] = acc;
    }
}

// ---------------- host ----------------
extern "C" void kernel_launch(void* const* d_in, const int* in_sizes, int n_in,
                              void* d_out, int out_size, void* d_ws, size_t ws_size,
                              hipStream_t stream) {
    (void)in_sizes; (void)n_in; (void)out_size; (void)ws_size;
    const float* inp = (const float*)d_in[0];
    LayerParams lp;
    for (int l = 0; l < 6; ++l) {
        lp.tseq[l] = (const float*)d_in[1 + 3*l];
        lp.gw[l]   = (const float*)d_in[2 + 3*l];
        lp.gb[l]   = (const float*)d_in[3 + 3*l];
    }
    const float* fcw = (const float*)d_in[19];
    const float* fcb = (const float*)d_in[20];

    char* w = (char*)d_ws;
    float* sums = (float*)(w + OFF_SUMS);
    int* hist = (int*)(w + OFF_HIST);
    int2* tab1 = (int2*)(w + OFF_TAB1);
    int2* tab2 = (int2*)(w + OFF_TAB2);
    float* pad1 = (float*)(w + OFF_PAD1);
    float* pad2 = (float*)(w + OFF_PAD2);
    float* dt = (float*)(w + OFF_DT);
    unsigned long long* key = (unsigned long long*)(w + OFF_KEY);
    int* rootd = (int*)(w + OFF_ROOT);
    int* comp = (int*)(w + OFF_COMP);
    unsigned long long* hp = (unsigned long long*)(w + OFF_HP);
    unsigned long long* hb = (unsigned long long*)(w + OFF_HB);
    int* py = (int*)(w + OFF_PY);
    int* pd = (int*)(w + OFF_PD);
    float* pp = (float*)(w + OFF_PP);
    int4* sel = (int4*)(w + OFF_SEL);
    float* xbuf = (float*)(w + OFF_X);

    hipLaunchKernelGGL(k_sums, dim3(6), dim3(256), 0, stream, inp, sums);
    hipLaunchKernelGGL(k_offsets, dim3(2), dim3(1024), 0, stream, hist, tab1, tab2);
    const int padTot = 6 * (PN1v + PN2v);
    hipLaunchKernelGGL(k_pad, dim3((padTot + 255) / 256), dim3(256), 0, stream, inp, pad1, pad2);
    hipLaunchKernelGGL(k_init, dim3((NFIELD*HSIZE + 255) / 256), dim3(256), 0, stream, hp, hb);
    hipLaunchKernelGGL(k_dtm, dim3(NPIX/256, NFIELD), dim3(256), 0, stream, sums, tab1, tab2, pad1, pad2, dt, key);
    hipLaunchKernelGGL(k_descent, dim3(NPIX/256, NFIELD), dim3(256), 0, stream, key, rootd);
    hipLaunchKernelGGL(k_jump, dim3(NFIELD), dim3(1024), 0, stream, rootd);
    hipLaunchKernelGGL(k_edges, dim3(NPIX/256, NFIELD), dim3(256), 0, stream, key, rootd, hp, hb);
    hipLaunchKernelGGL(k_finish, dim3(NFIELD), dim3(512), 0, stream, dt, key, rootd, comp, hp, hb, py, pd, pp, sel);
    hipLaunchKernelGGL(k_feat, dim3(NFIELD), dim3(64), 0, stream, dt, sel, lp, xbuf);
    hipLaunchKernelGGL(k_final, dim3(1), dim3(512), 0, stream, xbuf, fcw, fcb, (float*)d_out);
}

// Round 2
// 1445.643 us; speedup vs baseline: 1.8673x; 1.8673x over previous
//
#include <hip/hip_runtime.h>
#include <stdint.h>

#define HWDIM 224
#define NPIX (HWDIM*HWDIM)
#define NFIELD 12
#define TT 25

#define R1v 37
#define PW1v (HWDIM + 2*R1v)        /* 298 */
#define C1v  (PW1v + 1)             /* 299 */
#define R2v 74
#define PW2v (HWDIM + 2*R2v)        /* 372 */
#define C2v  (PW2v + 1)             /* 373 */

#define HSIZE 16384
#define FCAP 4096
#define RHASH 4096

struct LayerParams {
    const float* tseq[6];
    const float* gw[6];
    const float* gb[6];
};

// ---------------- workspace layout ----------------
constexpr size_t alup(size_t x) { return (x + 255) & ~(size_t)255; }
constexpr size_t SZPA = (size_t)6*PW1v*C1v*4;   // one g0 prefix array bytes
constexpr size_t SZPB = (size_t)6*PW2v*C2v*4;   // one g1 prefix array bytes
constexpr size_t OFF_SUMS = 0;
constexpr size_t OFF_P0A = alup(OFF_SUMS + 8*4);
constexpr size_t OFF_P1A = alup(OFF_P0A + SZPA);
constexpr size_t OFF_P2A = alup(OFF_P1A + SZPA);
constexpr size_t OFF_P0B = alup(OFF_P2A + SZPA);
constexpr size_t OFF_P1B = alup(OFF_P0B + SZPB);
constexpr size_t OFF_P2B = alup(OFF_P1B + SZPB);
constexpr size_t OFF_DT   = alup(OFF_P2B + SZPB);
constexpr size_t OFF_KEY  = alup(OFF_DT   + (size_t)NFIELD*NPIX*4);
constexpr size_t OFF_ROOT = alup(OFF_KEY  + (size_t)NFIELD*NPIX*8);
constexpr size_t OFF_HP   = alup(OFF_ROOT + (size_t)NFIELD*NPIX*4);
constexpr size_t OFF_HB   = alup(OFF_HP   + (size_t)NFIELD*HSIZE*8);
constexpr size_t OFF_SEL  = alup(OFF_HB   + (size_t)NFIELD*HSIZE*8);
constexpr size_t OFF_X    = alup(OFF_SEL  + (size_t)NFIELD*64*16);

// ---------------- kernels ----------------

__global__ __launch_bounds__(256) void k_sums(const float* __restrict__ inp, float* __restrict__ sums) {
    int img = blockIdx.x; // 0..5 = b*3+c
    const float* p = inp + (size_t)img * NPIX;
    __shared__ float red[256];
    float s = 0.f;
    for (int i = threadIdx.x; i < NPIX; i += 256) s += p[i];
    red[threadIdx.x] = s; __syncthreads();
    for (int w = 128; w > 0; w >>= 1) {
        if (threadIdx.x < w) red[threadIdx.x] += red[threadIdx.x + w];
        __syncthreads();
    }
    if (threadIdx.x == 0) sums[img] = red[0];
}

// per-row prefix sums of w, w*x', w*x'^2 over the (implicitly zero-padded) image.
// P[row][k] = sum over x' in [0, k). Accumulate in double, store f32.
__global__ __launch_bounds__(256) void k_prefix(const float* __restrict__ inp,
        float* __restrict__ p0a, float* __restrict__ p1a, float* __restrict__ p2a,
        float* __restrict__ p0b, float* __restrict__ p1b, float* __restrict__ p2b) {
    int t = blockIdx.x * 256 + threadIdx.x;
    const int tot0 = 6 * PW1v;
    const int tot = tot0 + 6 * PW2v;
    if (t >= tot) return;
    int g = (t >= tot0);
    int rem = g ? (t - tot0) : t;
    const int PW = g ? PW2v : PW1v, R = g ? R2v : R1v, C = PW + 1;
    int img = rem / PW, row = rem % PW;
    float* P0 = (g ? p0b : p0a) + ((size_t)img*PW + row) * C;
    float* P1 = (g ? p1b : p1a) + ((size_t)img*PW + row) * C;
    float* P2 = (g ? p2b : p2a) + ((size_t)img*PW + row) * C;
    int iy = row - R;
    bool rowok = ((unsigned)iy < HWDIM);
    const float* src = inp + (size_t)img*NPIX + (size_t)(rowok ? iy : 0)*HWDIM;
    double a0 = 0.0, a1 = 0.0, a2 = 0.0;
    P0[0] = 0.f; P1[0] = 0.f; P2[0] = 0.f;
    for (int k = 1; k <= PW; ++k) {
        int xp = k - 1;
        int ix = xp - R;
        float v = (rowok && (unsigned)ix < HWDIM) ? src[ix] : 0.f;
        double xd = (double)xp;
        a0 += v; a1 += v * xd; a2 += v * xd * xd;
        P0[k] = (float)a0; P1[k] = (float)a1; P2[k] = (float)a2;
    }
}

__global__ __launch_bounds__(256) void k_init(unsigned long long* __restrict__ hp, unsigned long long* __restrict__ hb) {
    size_t i = (size_t)blockIdx.x * 256 + threadIdx.x;
    if (i < (size_t)NFIELD * HSIZE) { hp[i] = ~0ull; hb[i] = ~0ull; }
}

// mass of region {dy^2+dx^2 <= X, |dy|<=R, |dx|<=R} around the pixel, via P0 range sums.
__device__ __forceinline__ float disc_mass(int X, const float* __restrict__ cp0, int C, int R,
                                           const unsigned char* __restrict__ tbl) {
    float m = 0.f;
    if (X >= 0) { int K = min((int)tbl[X], R); m = cp0[K+1] - cp0[-K]; }
    for (int dyy = 1; dyy <= R; ++dyy) {
        int t = X - dyy*dyy;
        if (__all(t < 0)) break;
        if (t >= 0) {
            int K = min((int)tbl[t], R);
            int o = dyy * C;
            const float* u = cp0 - o;
            const float* d = cp0 + o;
            m += u[K+1] - u[-K];
            m += d[K+1] - d[-K];
        }
    }
    return m;
}

__global__ __launch_bounds__(256) void k_dtm(const float* __restrict__ sums,
        const float* __restrict__ p0a, const float* __restrict__ p1a, const float* __restrict__ p2a,
        const float* __restrict__ p0b, const float* __restrict__ p1b, const float* __restrict__ p2b,
        float* __restrict__ dt, unsigned long long* __restrict__ key) {
    // heavy-first block order: first 6*196 blocks are the m0=0.2 fields (4x the work)
    int bid = blockIdx.x;
    int f, blk;
    if (bid < 6*196) { int q = bid / 196; f = 6 + q; blk = bid - q*196; }
    else { int r2 = bid - 6*196; int q = r2 / 196; f = q; blk = r2 - q*196; }
    const int layer = f >> 1, b = f & 1;
    const int g = layer / 3, c = layer % 3;
    const int img = b*3 + c;
    const int R = g ? R2v : R1v, PW = g ? PW2v : PW1v, C = PW + 1;
    const int R2 = 2*R*R;
    const int NTB = R2 + 2;
    __shared__ unsigned char tbl[2*R2v*R2v + 2];
    for (int t = threadIdx.x; t < NTB; t += 256) {
        int k = (int)sqrtf((float)t);
        while ((k+1)*(k+1) <= t) ++k;
        while (k*k > t) --k;
        tbl[t] = (unsigned char)k;
    }
    __syncthreads();
    const float thr = (g ? 0.2f : 0.05f) * sums[img];
    const int p = blk*256 + threadIdx.x;
    const int y = p / HWDIM, x = p % HWDIM;
    const int xc = x + R, yr = y + R;
    const float* P0 = (g ? p0b : p0a) + (size_t)img*PW*C;
    const float* P1 = (g ? p1b : p1a) + (size_t)img*PW*C;
    const float* P2 = (g ? p2b : p2a) + (size_t)img*PW*C;
    const float* cp0 = P0 + (size_t)yr*C + xc;
    const float* cp1 = P1 + (size_t)yr*C + xc;
    const float* cp2 = P2 + (size_t)yr*C + xc;

    // lower_bound over integer X: smallest X with mass(<=X) >= thr; sentinel R2+1 = no crossing
    int lo = 0, hi = R2 + 1;
    const int ITERS = g ? 14 : 12;
    for (int it = 0; it < ITERS; ++it) {
        int mid = (lo + hi) >> 1;
        float m = disc_mass(mid, cp0, C, R, tbl);
        if (lo < hi) { if (m >= thr) hi = mid; else lo = mid + 1; }
    }
    const int D = lo;
    const bool cross = (D <= R2);
    const int Xin = cross ? (D - 1) : R2;

    // weighted pass at Xin: mass_in and wsum_in
    float m_in = 0.f, ws = 0.f;
    const float c2n = -2.f * (float)xc;
    const int xc2i = xc * xc;
    if (Xin >= 0) {
        int K = min((int)tbl[Xin], R);
        float s0 = cp0[K+1] - cp0[-K];
        float s1 = cp1[K+1] - cp1[-K];
        float s2 = cp2[K+1] - cp2[-K];
        m_in += s0;
        ws += fmaf((float)xc2i, s0, fmaf(c2n, s1, s2));
    }
    for (int dyy = 1; dyy <= R; ++dyy) {
        int t = Xin - dyy*dyy;
        if (__all(t < 0)) break;
        if (t >= 0) {
            int K = min((int)tbl[t], R);
            int o = dyy * C;
            float c1 = (float)(dyy*dyy + xc2i);
            {
                const float* q0 = cp0 - o; const float* q1 = cp1 - o; const float* q2 = cp2 - o;
                float s0 = q0[K+1] - q0[-K];
                float s1 = q1[K+1] - q1[-K];
                float s2 = q2[K+1] - q2[-K];
                m_in += s0;
                ws += fmaf(c1, s0, fmaf(c2n, s1, s2));
            }
            {
                const float* q0 = cp0 + o; const float* q1 = cp1 + o; const float* q2 = cp2 + o;
                float s0 = q0[K+1] - q0[-K];
                float s1 = q1[K+1] - q1[-K];
                float s2 = q2[K+1] - q2[-K];
                m_in += s0;
                ws += fmaf(c1, s0, fmaf(c2n, s1, s2));
            }
        }
    }
    float s = cross ? (ws + (float)D * (thr - m_in)) : ws;
    float dtm2 = s / thr;
    float d = sqrtf(fmaxf(dtm2, 0.f));
    dt[(size_t)f*NPIX + p] = d;
    key[(size_t)f*NPIX + p] = ((unsigned long long)__float_as_uint(d) << 32) | (unsigned)p;
}

__global__ __launch_bounds__(256) void k_descent(const unsigned long long* __restrict__ key, int* __restrict__ rootd) {
    const int f = blockIdx.y;
    const int p = blockIdx.x * 256 + threadIdx.x;
    const unsigned long long* k = key + (size_t)f*NPIX;
    unsigned long long best = k[p]; int bi = p;
    const int y = p / HWDIM, x = p % HWDIM;
    if (y > 0)        { unsigned long long t = k[p - HWDIM]; if (t < best) { best = t; bi = p - HWDIM; } }
    if (y < HWDIM-1)  { unsigned long long t = k[p + HWDIM]; if (t < best) { best = t; bi = p + HWDIM; } }
    if (x > 0)        { unsigned long long t = k[p - 1];     if (t < best) { best = t; bi = p - 1; } }
    if (x < HWDIM-1)  { unsigned long long t = k[p + 1];     if (t < best) { best = t; bi = p + 1; } }
    rootd[(size_t)f*NPIX + p] = bi;
}

__global__ __launch_bounds__(1024) void k_jump(int* __restrict__ rootd) {
    int* r = rootd + (size_t)blockIdx.x * NPIX;
    for (int pass = 0; pass < 18; ++pass) {
        for (int p = threadIdx.x; p < NPIX; p += 1024) r[p] = r[r[p]];
        __syncthreads();
    }
}

__device__ inline unsigned hash64(unsigned long long x) {
    x ^= x >> 33; x *= 0xff51afd7ed558ccdULL;
    x ^= x >> 33; x *= 0xc4ceb9fe1a85ec53ULL;
    x ^= x >> 33;
    return (unsigned)x;
}

__global__ __launch_bounds__(256) void k_edges(const unsigned long long* __restrict__ key, const int* __restrict__ rootd,
        unsigned long long* __restrict__ hpair, unsigned long long* __restrict__ hbest) {
    const int f = blockIdx.y;
    const int p = blockIdx.x * 256 + threadIdx.x;
    const unsigned long long* k = key + (size_t)f*NPIX;
    const int* r = rootd + (size_t)f*NPIX;
    unsigned long long* hp = hpair + (size_t)f*HSIZE;
    unsigned long long* hb = hbest + (size_t)f*HSIZE;
    const int y = p / HWDIM, x = p % HWDIM;
    const int rp = r[p];
    const unsigned long long kp = k[p];
    #pragma unroll
    for (int e = 0; e < 2; ++e) {
        int q;
        if (e == 0) { if (x >= HWDIM-1) continue; q = p + 1; }
        else        { if (y >= HWDIM-1) continue; q = p + HWDIM; }
        int rq = r[q];
        if (rq == rp) continue;
        unsigned long long kq = k[q];
        unsigned long long ek = (kp > kq) ? kp : kq;      // key of death (later) endpoint
        int ra = min(rp, rq), rb = max(rp, rq);
        unsigned long long pk = ((unsigned long long)(unsigned)ra << 32) | (unsigned)rb;
        unsigned h = hash64(pk) & (HSIZE - 1);
        for (int probe = 0; probe < HSIZE; ++probe) {
            unsigned long long old = atomicCAS(&hp[h], ~0ull, pk);
            if (old == ~0ull || old == pk) { atomicMin(&hb[h], ek); break; }
            h = (h + 1) & (HSIZE - 1);
        }
    }
}

__device__ __forceinline__ void bitonic4096(unsigned long long* ek, int tid) {
    for (int k = 2; k <= FCAP; k <<= 1) {
        for (int j = k >> 1; j > 0; j >>= 1) {
            for (int i = tid; i < FCAP; i += 512) {
                int ixj = i ^ j;
                if (ixj > i) {
                    unsigned long long a = ek[i], b = ek[ixj];
                    if (((i & k) == 0) ? (a > b) : (a < b)) { ek[i] = b; ek[ixj] = a; }
                }
            }
            __syncthreads();
        }
    }
}

__global__ __launch_bounds__(512) void k_finish(const float* __restrict__ dt, const unsigned long long* __restrict__ key,
        const int* __restrict__ rootd,
        const unsigned long long* __restrict__ hpair, const unsigned long long* __restrict__ hbest,
        int4* __restrict__ sel) {
    const int f = blockIdx.x;
    const int tid = threadIdx.x; const int bs = 512;
    const float* dtf = dt + (size_t)f*NPIX;
    const unsigned long long* kf = key + (size_t)f*NPIX;
    const int* rf = rootd + (size_t)f*NPIX;
    const unsigned long long* hp = hpair + (size_t)f*HSIZE;
    const unsigned long long* hb = hbest + (size_t)f*HSIZE;

    __shared__ unsigned long long ek[FCAP];   // 32KB sort keys
    __shared__ unsigned int epk[FCAP];        // 16KB (ra<<16)|rb
    __shared__ unsigned short eru[FCAP];      // 8KB  root of death pixel
    __shared__ int rhk[RHASH];                // 16KB root-pixel hash keys (-1 empty)
    __shared__ short ufp[RHASH];              // 8KB  union-find parent (slot)
    __shared__ float rdt[RHASH];              // 16KB dt at root
    __shared__ unsigned int pyd[FCAP];        // 16KB (young<<16)|death
    __shared__ float ppr[FCAP];               // 16KB persistence
    __shared__ unsigned long long redk[512];
    __shared__ float redf[512];
    __shared__ int redi[512];
    __shared__ int cnt_s, pc_s;
    __shared__ int gmin_s, gmax_s; __shared__ float gminf_s, gmaxf_s;

    for (int i = tid; i < RHASH; i += bs) rhk[i] = -1;
    if (tid == 0) { cnt_s = 0; pc_s = 0; }

    // global min/max over key
    unsigned long long mymin = ~0ull;
    float bf = -1.f; int bi = 0x7fffffff;
    for (int p = tid; p < NPIX; p += bs) {
        unsigned long long kk = kf[p];
        if (kk < mymin) mymin = kk;
        float v = __uint_as_float((unsigned)(kk >> 32));
        if (v > bf || (v == bf && p < bi)) { bf = v; bi = p; }
    }
    redk[tid] = mymin; redf[tid] = bf; redi[tid] = bi;
    __syncthreads();
    for (int w = 256; w > 0; w >>= 1) {
        if (tid < w) {
            if (redk[tid + w] < redk[tid]) redk[tid] = redk[tid + w];
            float vf = redf[tid + w]; int vi = redi[tid + w];
            if (vf > redf[tid] || (vf == redf[tid] && vi < redi[tid])) { redf[tid] = vf; redi[tid] = vi; }
        }
        __syncthreads();
    }
    if (tid == 0) {
        gmin_s = (int)(unsigned)redk[0];
        gminf_s = __uint_as_float((unsigned)(redk[0] >> 32));
        gmax_s = redi[0]; gmaxf_s = redf[0];
    }
    __syncthreads();

    // compact hash table into LDS + insert roots into dense hash
    for (int i = tid; i < HSIZE; i += bs) {
        unsigned long long pk = hp[i];
        if (pk != ~0ull) {
            int slot = atomicAdd(&cnt_s, 1);
            if (slot < FCAP) {
                unsigned long long e = hb[i];
                unsigned u = (unsigned)e & 0xFFFFFFFFu;  // death pixel (< 65536)
                ek[slot] = (e & 0xFFFFFFFF00000000ull) | ((unsigned long long)(u & 0xFFFFu) << 16) | (unsigned)slot;
                int ra = (int)(pk >> 32), rb = (int)(pk & 0xFFFFFFFFu);
                epk[slot] = ((unsigned)ra << 16) | (unsigned)rb;
                eru[slot] = (unsigned short)rf[u];
                #pragma unroll
                for (int pass = 0; pass < 2; ++pass) {
                    int r = pass ? rb : ra;
                    unsigned h = ((unsigned)r * 2654435761u) & (RHASH - 1);
                    for (int pr = 0; pr < RHASH; ++pr) {
                        int old = atomicCAS(&rhk[h], -1, r);
                        if (old == -1 || old == r) break;
                        h = (h + 1) & (RHASH - 1);
                    }
                }
            }
        }
    }
    __syncthreads();
    int cnt = min(cnt_s, FCAP);
    for (int i = cnt + tid; i < FCAP; i += bs) ek[i] = ~0ull;
    for (int s2 = tid; s2 < RHASH; s2 += bs) {
        ufp[s2] = (short)s2;
        int r = rhk[s2];
        rdt[s2] = (r >= 0) ? dtf[r] : 0.f;
    }
    __syncthreads();

    bitonic4096(ek, tid);   // ascending by (death dt, death pixel, slot)

    // serial Kruskal (elder rule) in LDS
    if (tid == 0) {
        int pc = 0;
        for (int i = 0; i < cnt; ++i) {
            unsigned long long e = ek[i];
            int idx = (int)(e & 0xFFFFu);
            int u = (int)((e >> 16) & 0xFFFFu);
            unsigned pk2 = epk[idx];
            int ra = (int)(pk2 >> 16), rb = (int)(pk2 & 0xFFFFu);
            int ru = eru[idx];
            int rv = (ru == ra) ? rb : ra;
            int sa = -1, sb = -1;
            { unsigned h = ((unsigned)ru * 2654435761u) & (RHASH - 1);
              for (int pr = 0; pr < RHASH; ++pr) { int v = rhk[h]; if (v == ru) { sa = (int)h; break; } if (v == -1) break; h = (h + 1) & (RHASH - 1); } }
            { unsigned h = ((unsigned)rv * 2654435761u) & (RHASH - 1);
              for (int pr = 0; pr < RHASH; ++pr) { int v = rhk[h]; if (v == rv) { sb = (int)h; break; } if (v == -1) break; h = (h + 1) & (RHASH - 1); } }
            if (sa < 0 || sb < 0) continue;
            while (ufp[sa] != sa) { short g2 = ufp[ufp[sa]]; ufp[sa] = g2; sa = g2; }
            while (ufp[sb] != sb) { short g2 = ufp[ufp[sb]]; ufp[sb] = g2; sb = g2; }
            if (sa == sb) continue;
            float fa = rdt[sa], fb = rdt[sb];
            int elder, young;
            if (fa <= fb) { elder = sa; young = sb; } else { elder = sb; young = sa; }
            ufp[young] = (short)elder;
            float pers = __uint_as_float((unsigned)(e >> 32)) - rdt[young];
            if (pers > 0.f && pc < FCAP - 1) {
                pyd[pc] = ((unsigned)rhk[young] << 16) | (unsigned)u;
                ppr[pc] = pers; ++pc;
            }
        }
        pyd[pc] = ((unsigned)gmin_s << 16) | (unsigned)gmax_s;
        ppr[pc] = gmaxf_s - gminf_s; ++pc;
        pc_s = pc;
    }
    __syncthreads();
    const int pc = pc_s;

    // top-64 by persistence: descending sort via key = (~persbits, idx)
    for (int i = tid; i < FCAP; i += bs) {
        if (i < pc && ppr[i] > 0.f)
            ek[i] = ((unsigned long long)(0xFFFFFFFFu - __float_as_uint(ppr[i])) << 32) | (unsigned)i;
        else ek[i] = ~0ull;
    }
    __syncthreads();
    bitonic4096(ek, tid);
    for (int slot = tid; slot < 64; slot += bs) {
        unsigned long long e = ek[slot];
        int4 o;
        if (e != ~0ull) {
            int i = (int)(e & 0xFFFFFFFFu);
            unsigned pd2 = pyd[i];
            o.x = (int)(pd2 >> 16); o.y = (int)(pd2 & 0xFFFFu); o.z = 1; o.w = 0;
        } else { o.x = 0; o.y = 0; o.z = 0; o.w = 0; }
        sel[f*64 + slot] = o;
    }
}

__global__ __launch_bounds__(64) void k_feat(const float* __restrict__ dt, const int4* __restrict__ sel,
        LayerParams lp, float* __restrict__ x) {
    const int f = blockIdx.x; const int layer = f >> 1, b = f & 1;
    const float* dtf = dt + (size_t)f*NPIX;
    __shared__ float birth[64], death[64], feat[2*TT];
    const int tid = threadIdx.x;
    int4 s = sel[f*64 + tid];
    float bv = dtf[s.x];
    float dv = s.z ? dtf[s.y] : bv;
    birth[tid] = bv; death[tid] = dv;
    __syncthreads();
    if (tid < TT) {
        float t = lp.tseq[layer][tid];
        float m1 = 0.f, m2 = 0.f;
        for (int m = 0; m < 64; ++m) {
            float v = fmaxf(fminf(t - birth[m], death[m] - t), 0.f);
            if (v > m1) { m2 = m1; m1 = v; } else if (v > m2) m2 = v;
        }
        feat[tid] = m1; feat[TT + tid] = m2;
    }
    __syncthreads();
    if (tid < 50) {
        const float* w = lp.gw[layer] + tid * 50;
        float acc = lp.gb[layer][tid];
        #pragma unroll
        for (int j = 0; j < 50; ++j) acc = fmaf(feat[j], w[j], acc);
        x[b*300 + layer*50 + tid] = acc;
    }
}

__global__ __launch_bounds__(512) void k_final(const float* __restrict__ x, const float* __restrict__ fcw,
        const float* __restrict__ fcb, float* __restrict__ out) {
    __shared__ float rl[2][300];
    const int tid = threadIdx.x;
    if (tid < 300) {
        float a0 = x[tid], a1 = x[300 + tid];
        out[14 + tid] = fabsf(a0) + fabsf(a1);
        rl[0][tid] = fmaxf(a0, 0.f);
        rl[1][tid] = fmaxf(a1, 0.f);
    }
    __syncthreads();
    if (tid < 14) {
        int b = tid / 7, i = tid % 7;
        float acc = fcb[i];
        const float* w = fcw + i * 300;
        for (int j = 0; j < 300; ++j) acc = fmaf(rl[b][j], w[j], acc);
        out[b*7 + i] = acc;
    }
}

// ---------------- host ----------------
extern "C" void kernel_launch(void* const* d_in, const int* in_sizes, int n_in,
                              void* d_out, int out_size, void* d_ws, size_t ws_size,
                              hipStream_t stream) {
    (void)in_sizes; (void)n_in; (void)out_size; (void)ws_size;
    const float* inp = (const float*)d_in[0];
    LayerParams lp;
    for (int l = 0; l < 6; ++l) {
        lp.tseq[l] = (const float*)d_in[1 + 3*l];
        lp.gw[l]   = (const float*)d_in[2 + 3*l];
        lp.gb[l]   = (const float*)d_in[3 + 3*l];
    }
    const float* fcw = (const float*)d_in[19];
    const float* fcb = (const float*)d_in[20];

    char* w = (char*)d_ws;
    float* sums = (float*)(w + OFF_SUMS);
    float* p0a = (float*)(w + OFF_P0A);
    float* p1a = (float*)(w + OFF_P1A);
    float* p2a = (float*)(w + OFF_P2A);
    float* p0b = (float*)(w + OFF_P0B);
    float* p1b = (float*)(w + OFF_P1B);
    float* p2b = (float*)(w + OFF_P2B);
    float* dt = (float*)(w + OFF_DT);
    unsigned long long* key = (unsigned long long*)(w + OFF_KEY);
    int* rootd = (int*)(w + OFF_ROOT);
    unsigned long long* hp = (unsigned long long*)(w + OFF_HP);
    unsigned long long* hb = (unsigned long long*)(w + OFF_HB);
    int4* sel = (int4*)(w + OFF_SEL);
    float* xbuf = (float*)(w + OFF_X);

    hipLaunchKernelGGL(k_sums, dim3(6), dim3(256), 0, stream, inp, sums);
    const int prefRows = 6*PW1v + 6*PW2v;
    hipLaunchKernelGGL(k_prefix, dim3((prefRows + 255) / 256), dim3(256), 0, stream,
                       inp, p0a, p1a, p2a, p0b, p1b, p2b);
    hipLaunchKernelGGL(k_init, dim3((NFIELD*HSIZE + 255) / 256), dim3(256), 0, stream, hp, hb);
    hipLaunchKernelGGL(k_dtm, dim3(NFIELD * (NPIX/256)), dim3(256), 0, stream,
                       sums, p0a, p1a, p2a, p0b, p1b, p2b, dt, key);
    hipLaunchKernelGGL(k_descent, dim3(NPIX/256, NFIELD), dim3(256), 0, stream, key, rootd);
    hipLaunchKernelGGL(k_jump, dim3(NFIELD), dim3(1024), 0, stream, rootd);
    hipLaunchKernelGGL(k_edges, dim3(NPIX/256, NFIELD), dim3(256), 0, stream, key, rootd, hp, hb);
    hipLaunchKernelGGL(k_finish, dim3(NFIELD), dim3(512), 0, stream, dt, key, rootd, hp, hb, sel);
    hipLaunchKernelGGL(k_feat, dim3(NFIELD), dim3(64), 0, stream, dt, sel, lp, xbuf);
    hipLaunchKernelGGL(k_final, dim3(1), dim3(512), 0, stream, xbuf, fcw, fcb, (float*)d_out);
}

// Round 3
// 1143.635 us; speedup vs baseline: 2.3604x; 1.2641x over previous
//
#include <hip/hip_runtime.h>
#include <stdint.h>

#define HWDIM 224
#define NPIX (HWDIM*HWDIM)
#define NFIELD 12
#define TT 25
#define BLKF (NPIX/256)            /* 196 blocks per field */

#define R1v 37
#define PW1v (HWDIM + 2*R1v)        /* 298 */
#define C1v  (PW1v + 1)             /* 299 */
#define R2v 74
#define PW2v (HWDIM + 2*R2v)        /* 372 */
#define C2v  (PW2v + 1)             /* 373 */

#define HSIZE 16384
#define FCAP 4096
#define RHASH 4096

struct LayerParams {
    const float* tseq[6];
    const float* gw[6];
    const float* gb[6];
};

// ---------------- workspace layout ----------------
constexpr size_t alup(size_t x) { return (x + 255) & ~(size_t)255; }
constexpr size_t SZPA = (size_t)6*PW1v*C1v*4;   // one g0 prefix array bytes
constexpr size_t SZPB = (size_t)6*PW2v*C2v*4;   // one g1 prefix array bytes
constexpr size_t OFF_SUMS = 0;
constexpr size_t OFF_P0A = alup(OFF_SUMS + 8*4);
constexpr size_t OFF_P1A = alup(OFF_P0A + SZPA);
constexpr size_t OFF_P2A = alup(OFF_P1A + SZPA);
constexpr size_t OFF_P0B = alup(OFF_P2A + SZPA);
constexpr size_t OFF_P1B = alup(OFF_P0B + SZPB);
constexpr size_t OFF_P2B = alup(OFF_P1B + SZPB);
constexpr size_t OFF_DT   = alup(OFF_P2B + SZPB);
constexpr size_t OFF_KEY  = alup(OFF_DT   + (size_t)NFIELD*NPIX*4);
constexpr size_t OFF_ROOT = alup(OFF_KEY  + (size_t)NFIELD*NPIX*8);
constexpr size_t OFF_HP   = alup(OFF_ROOT + (size_t)NFIELD*NPIX*4);
constexpr size_t OFF_HB   = alup(OFF_HP   + (size_t)NFIELD*HSIZE*8);
constexpr size_t OFF_SEL  = alup(OFF_HB   + (size_t)NFIELD*HSIZE*8);
constexpr size_t OFF_X    = alup(OFF_SEL  + (size_t)NFIELD*64*16);

// ---------------- kernels ----------------

__global__ __launch_bounds__(256) void k_sums(const float* __restrict__ inp, float* __restrict__ sums) {
    int img = blockIdx.x; // 0..5 = b*3+c
    const float* p = inp + (size_t)img * NPIX;
    __shared__ float red[256];
    float s = 0.f;
    for (int i = threadIdx.x; i < NPIX; i += 256) s += p[i];
    red[threadIdx.x] = s; __syncthreads();
    for (int w = 128; w > 0; w >>= 1) {
        if (threadIdx.x < w) red[threadIdx.x] += red[threadIdx.x + w];
        __syncthreads();
    }
    if (threadIdx.x == 0) sums[img] = red[0];
}

// One 64-lane wave per padded row. Prefix sums of w, w*x', w*x'^2 (double accum,
// f32 store), coalesced loads and coalesced row-contiguous stores.
__global__ __launch_bounds__(64) void k_prefix(const float* __restrict__ inp,
        float* __restrict__ p0a, float* __restrict__ p1a, float* __restrict__ p2a,
        float* __restrict__ p0b, float* __restrict__ p1b, float* __restrict__ p2b) {
    int bidx = blockIdx.x;
    const int tot0 = 6 * PW1v;
    int g = (bidx >= tot0);
    int rem = g ? (bidx - tot0) : bidx;
    const int PW = g ? PW2v : PW1v, R = g ? R2v : R1v, C = PW + 1;
    int img = rem / PW, row = rem % PW;
    float* P0 = (g ? p0b : p0a) + ((size_t)img*PW + row) * C;
    float* P1 = (g ? p1b : p1a) + ((size_t)img*PW + row) * C;
    float* P2 = (g ? p2b : p2a) + ((size_t)img*PW + row) * C;
    int iy = row - R;
    bool rowok = ((unsigned)iy < HWDIM);
    const float* src = inp + (size_t)img*NPIX + (size_t)(rowok ? iy : 0)*HWDIM;
    const int lane = threadIdx.x;
    if (lane == 0) { P0[0] = 0.f; P1[0] = 0.f; P2[0] = 0.f; }
    double c0 = 0.0, c1 = 0.0, c2 = 0.0;
    for (int i = 0; i < 6; ++i) {
        int k = i*64 + lane;            // element index == xp
        float v = 0.f;
        if (k < PW && rowok) { int ix = k - R; if ((unsigned)ix < HWDIM) v = src[ix]; }
        double xd = (double)k;
        double w0 = v, w1 = v*xd, w2 = v*xd*xd;
        #pragma unroll
        for (int off = 1; off < 64; off <<= 1) {
            double t0 = __shfl_up(w0, off), t1 = __shfl_up(w1, off), t2 = __shfl_up(w2, off);
            if (lane >= off) { w0 += t0; w1 += t1; w2 += t2; }
        }
        if (k < PW) {
            P0[k+1] = (float)(c0 + w0); P1[k+1] = (float)(c1 + w1); P2[k+1] = (float)(c2 + w2);
        }
        c0 += __shfl(w0, 63); c1 += __shfl(w1, 63); c2 += __shfl(w2, 63);
    }
}

// mass of region {dy^2+dx^2 <= X, |dy|<=R, |dx|<=R} around the pixel, via P0 range sums.
__device__ __forceinline__ float disc_mass(int X, const float* __restrict__ cp0, int C, int R,
                                           const unsigned char* __restrict__ tbl) {
    float m = 0.f;
    if (X >= 0) { int K = min((int)tbl[X], R); m = cp0[K+1] - cp0[-K]; }
    for (int dyy = 1; dyy <= R; ++dyy) {
        int t = X - dyy*dyy;
        if (__all(t < 0)) break;
        if (t >= 0) {
            int K = min((int)tbl[t], R);
            int o = dyy * C;
            const float* u = cp0 - o;
            const float* d = cp0 + o;
            m += u[K+1] - u[-K];
            m += d[K+1] - d[-K];
        }
    }
    return m;
}

// XCD-pinned: blockIdx%8 selects the XCD (HW round-robin). XCD 0..5 own one
// g1 field each; XCD 6,7 own three g0 fields each -> per-field prefix arrays
// (1.1-1.7 MB) stay resident in that XCD's 4MB L2.
__global__ __launch_bounds__(256) void k_dtm(const float* __restrict__ sums,
        const float* __restrict__ p0a, const float* __restrict__ p1a, const float* __restrict__ p2a,
        const float* __restrict__ p0b, const float* __restrict__ p1b, const float* __restrict__ p2b,
        float* __restrict__ dt, unsigned long long* __restrict__ key) {
    const int xcd = blockIdx.x & 7, slot = blockIdx.x >> 3;
    int f, blk;
    if (xcd < 6) { if (slot >= BLKF) return; f = 6 + xcd; blk = slot; }
    else { if (slot >= 3*BLKF) return; int q = slot / BLKF; f = (xcd - 6)*3 + q; blk = slot - q*BLKF; }
    const int layer = f >> 1, b = f & 1;
    const int g = layer / 3, c = layer % 3;
    const int img = b*3 + c;
    const int R = g ? R2v : R1v, PW = g ? PW2v : PW1v, C = PW + 1;
    const int R2 = 2*R*R;
    const int NTB = R2 + 2;
    __shared__ unsigned char tbl[2*R2v*R2v + 2];
    for (int t = threadIdx.x; t < NTB; t += 256) {
        int k = (int)sqrtf((float)t);
        while ((k+1)*(k+1) <= t) ++k;
        while (k*k > t) --k;
        tbl[t] = (unsigned char)k;
    }
    __syncthreads();
    const float thr = (g ? 0.2f : 0.05f) * sums[img];
    const int p = blk*256 + threadIdx.x;
    const int y = p / HWDIM, x = p % HWDIM;
    const int xc = x + R, yr = y + R;
    const float* P0 = (g ? p0b : p0a) + (size_t)img*PW*C;
    const float* P1 = (g ? p1b : p1a) + (size_t)img*PW*C;
    const float* P2 = (g ? p2b : p2a) + (size_t)img*PW*C;
    const float* cp0 = P0 + (size_t)yr*C + xc;
    const float* cp1 = P1 + (size_t)yr*C + xc;
    const float* cp2 = P2 + (size_t)yr*C + xc;

    // lower_bound over integer X: smallest X with mass(<=X) >= thr; sentinel R2+1 = no crossing
    int lo = 0, hi = R2 + 1;
    const int ITERS = g ? 14 : 12;
    for (int it = 0; it < ITERS; ++it) {
        int mid = (lo + hi) >> 1;
        float m = disc_mass(mid, cp0, C, R, tbl);
        if (lo < hi) { if (m >= thr) hi = mid; else lo = mid + 1; }
    }
    const int D = lo;
    const bool cross = (D <= R2);
    const int Xin = cross ? (D - 1) : R2;

    // weighted pass at Xin: mass_in and wsum_in
    float m_in = 0.f, ws = 0.f;
    const float c2n = -2.f * (float)xc;
    const int xc2i = xc * xc;
    if (Xin >= 0) {
        int K = min((int)tbl[Xin], R);
        float s0 = cp0[K+1] - cp0[-K];
        float s1 = cp1[K+1] - cp1[-K];
        float s2 = cp2[K+1] - cp2[-K];
        m_in += s0;
        ws += fmaf((float)xc2i, s0, fmaf(c2n, s1, s2));
    }
    for (int dyy = 1; dyy <= R; ++dyy) {
        int t = Xin - dyy*dyy;
        if (__all(t < 0)) break;
        if (t >= 0) {
            int K = min((int)tbl[t], R);
            int o = dyy * C;
            float c1 = (float)(dyy*dyy + xc2i);
            {
                const float* q0 = cp0 - o; const float* q1 = cp1 - o; const float* q2 = cp2 - o;
                float s0 = q0[K+1] - q0[-K];
                float s1 = q1[K+1] - q1[-K];
                float s2 = q2[K+1] - q2[-K];
                m_in += s0;
                ws += fmaf(c1, s0, fmaf(c2n, s1, s2));
            }
            {
                const float* q0 = cp0 + o; const float* q1 = cp1 + o; const float* q2 = cp2 + o;
                float s0 = q0[K+1] - q0[-K];
                float s1 = q1[K+1] - q1[-K];
                float s2 = q2[K+1] - q2[-K];
                m_in += s0;
                ws += fmaf(c1, s0, fmaf(c2n, s1, s2));
            }
        }
    }
    float s = cross ? (ws + (float)D * (thr - m_in)) : ws;
    float dtm2 = s / thr;
    float d = sqrtf(fmaxf(dtm2, 0.f));
    dt[(size_t)f*NPIX + p] = d;
    key[(size_t)f*NPIX + p] = ((unsigned long long)__float_as_uint(d) << 32) | (unsigned)p;
}

__device__ inline unsigned hash64(unsigned long long x) {
    x ^= x >> 33; x *= 0xff51afd7ed558ccdULL;
    x ^= x >> 33; x *= 0xc4ceb9fe1a85ec53ULL;
    x ^= x >> 33;
    return (unsigned)x;
}

// Fused steepest-descent + pointer-jumping (ushort parent in LDS) + inter-basin
// edge extraction. One block per field.
__global__ __launch_bounds__(1024) void k_uf(const unsigned long long* __restrict__ key,
        int* __restrict__ rootd,
        unsigned long long* __restrict__ hpair, unsigned long long* __restrict__ hbest) {
    const int f = blockIdx.x;
    const unsigned long long* kf = key + (size_t)f*NPIX;
    unsigned long long* hp = hpair + (size_t)f*HSIZE;
    unsigned long long* hb = hbest + (size_t)f*HSIZE;
    __shared__ unsigned short par[NPIX];   // 100 KB
    const int tid = threadIdx.x;
    // descent
    for (int p = tid; p < NPIX; p += 1024) {
        unsigned long long best = kf[p]; int bi = p;
        const int y = p / HWDIM, x = p % HWDIM;
        if (y > 0)        { unsigned long long t = kf[p - HWDIM]; if (t < best) { best = t; bi = p - HWDIM; } }
        if (y < HWDIM-1)  { unsigned long long t = kf[p + HWDIM]; if (t < best) { best = t; bi = p + HWDIM; } }
        if (x > 0)        { unsigned long long t = kf[p - 1];     if (t < best) { best = t; bi = p - 1; } }
        if (x < HWDIM-1)  { unsigned long long t = kf[p + 1];     if (t < best) { best = t; bi = p + 1; } }
        par[p] = (unsigned short)bi;
    }
    __syncthreads();
    // pointer jumping in LDS; races are monotone-safe; 2^16 >= NPIX guarantees convergence
    for (int pass = 0; pass < 16; ++pass) {
        for (int p = tid; p < NPIX; p += 1024) par[p] = par[par[p]];
        __syncthreads();
    }
    // edges (right/down) between distinct basins + rootd writeback
    for (int p = tid; p < NPIX; p += 1024) {
        const int rp = par[p];
        rootd[(size_t)f*NPIX + p] = rp;
        const int y = p / HWDIM, x = p % HWDIM;
        const unsigned long long kp = kf[p];
        #pragma unroll
        for (int e = 0; e < 2; ++e) {
            int q;
            if (e == 0) { if (x >= HWDIM-1) continue; q = p + 1; }
            else        { if (y >= HWDIM-1) continue; q = p + HWDIM; }
            int rq = par[q];
            if (rq == rp) continue;
            unsigned long long kq = kf[q];
            unsigned long long ek = (kp > kq) ? kp : kq;      // key of death (later) endpoint
            int ra = min(rp, rq), rb = max(rp, rq);
            unsigned long long pk = ((unsigned long long)(unsigned)ra << 32) | (unsigned)rb;
            unsigned h = hash64(pk) & (HSIZE - 1);
            for (int probe = 0; probe < HSIZE; ++probe) {
                unsigned long long old = atomicCAS(&hp[h], ~0ull, pk);
                if (old == ~0ull || old == pk) { atomicMin(&hb[h], ek); break; }
                h = (h + 1) & (HSIZE - 1);
            }
        }
    }
}

__device__ __forceinline__ void bitonic4096(unsigned long long* ek, int tid) {
    for (int k = 2; k <= FCAP; k <<= 1) {
        for (int j = k >> 1; j > 0; j >>= 1) {
            for (int i = tid; i < FCAP; i += 512) {
                int ixj = i ^ j;
                if (ixj > i) {
                    unsigned long long a = ek[i], b = ek[ixj];
                    if (((i & k) == 0) ? (a > b) : (a < b)) { ek[i] = b; ek[ixj] = a; }
                }
            }
            __syncthreads();
        }
    }
}

__global__ __launch_bounds__(512) void k_finish(const float* __restrict__ dt, const unsigned long long* __restrict__ key,
        const int* __restrict__ rootd,
        const unsigned long long* __restrict__ hpair, const unsigned long long* __restrict__ hbest,
        int4* __restrict__ sel) {
    const int f = blockIdx.x;
    const int tid = threadIdx.x; const int bs = 512;
    const float* dtf = dt + (size_t)f*NPIX;
    const unsigned long long* kf = key + (size_t)f*NPIX;
    const int* rf = rootd + (size_t)f*NPIX;
    const unsigned long long* hp = hpair + (size_t)f*HSIZE;
    const unsigned long long* hb = hbest + (size_t)f*HSIZE;

    __shared__ unsigned long long ek[FCAP];   // 32KB sort keys
    __shared__ unsigned int epk[FCAP];        // 16KB (ra<<16)|rb
    __shared__ unsigned int eab[FCAP];        // 16KB (slot_ru<<16)|slot_rv
    __shared__ int rhk[RHASH];                // 16KB root-pixel hash keys (-1 empty)
    __shared__ short ufp[RHASH];              // 8KB  union-find parent (slot)
    __shared__ float rdt[RHASH];              // 16KB dt at root
    __shared__ unsigned int pyd[FCAP];        // 16KB (young<<16)|death
    __shared__ float ppr[FCAP];               // 16KB persistence
    __shared__ unsigned long long redk[512];
    __shared__ float redf[512];
    __shared__ int redi[512];
    __shared__ int cnt_s, pc_s;
    __shared__ int gmin_s, gmax_s; __shared__ float gminf_s, gmaxf_s;

    for (int i = tid; i < RHASH; i += bs) rhk[i] = -1;
    if (tid == 0) { cnt_s = 0; pc_s = 0; }

    // global min/max over key
    unsigned long long mymin = ~0ull;
    float bf = -1.f; int bi = 0x7fffffff;
    for (int p = tid; p < NPIX; p += bs) {
        unsigned long long kk = kf[p];
        if (kk < mymin) mymin = kk;
        float v = __uint_as_float((unsigned)(kk >> 32));
        if (v > bf || (v == bf && p < bi)) { bf = v; bi = p; }
    }
    redk[tid] = mymin; redf[tid] = bf; redi[tid] = bi;
    __syncthreads();
    for (int w = 256; w > 0; w >>= 1) {
        if (tid < w) {
            if (redk[tid + w] < redk[tid]) redk[tid] = redk[tid + w];
            float vf = redf[tid + w]; int vi = redi[tid + w];
            if (vf > redf[tid] || (vf == redf[tid] && vi < redi[tid])) { redf[tid] = vf; redi[tid] = vi; }
        }
        __syncthreads();
    }
    if (tid == 0) {
        gmin_s = (int)(unsigned)redk[0];
        gminf_s = __uint_as_float((unsigned)(redk[0] >> 32));
        gmax_s = redi[0]; gmaxf_s = redf[0];
    }
    __syncthreads();

    // Phase A: compact hash table into LDS + insert roots into dense hash
    for (int i = tid; i < HSIZE; i += bs) {
        unsigned long long pk = hp[i];
        if (pk != ~0ull) {
            int slot = atomicAdd(&cnt_s, 1);
            if (slot < FCAP) {
                unsigned long long e = hb[i];
                unsigned u = (unsigned)e & 0xFFFFu;  // death pixel (< 65536)
                ek[slot] = (e & 0xFFFFFFFF00000000ull) | ((unsigned long long)u << 16) | (unsigned)slot;
                int ra = (int)(pk >> 32), rb = (int)(pk & 0xFFFFFFFFu);
                epk[slot] = ((unsigned)ra << 16) | (unsigned)rb;
                #pragma unroll
                for (int pass = 0; pass < 2; ++pass) {
                    int r = pass ? rb : ra;
                    unsigned h = ((unsigned)r * 2654435761u) & (RHASH - 1);
                    for (int pr = 0; pr < RHASH; ++pr) {
                        int old = atomicCAS(&rhk[h], -1, r);
                        if (old == -1 || old == r) break;
                        h = (h + 1) & (RHASH - 1);
                    }
                }
            }
        }
    }
    __syncthreads();
    int cnt = min(cnt_s, FCAP);
    // Phase B (parallel): resolve per-edge (slot_ru, slot_rv)
    for (int s2 = tid; s2 < cnt; s2 += bs) {
        int u = (int)((ek[s2] >> 16) & 0xFFFFu);
        unsigned pk2 = epk[s2];
        int ra = (int)(pk2 >> 16), rb = (int)(pk2 & 0xFFFFu);
        int ru = rf[u];
        int rv = (ru == ra) ? rb : ra;
        int su = -1, sv = -1;
        { unsigned h = ((unsigned)ru * 2654435761u) & (RHASH - 1);
          for (int pr = 0; pr < RHASH; ++pr) { int v = rhk[h]; if (v == ru) { su = (int)h; break; } if (v == -1) break; h = (h + 1) & (RHASH - 1); } }
        { unsigned h = ((unsigned)rv * 2654435761u) & (RHASH - 1);
          for (int pr = 0; pr < RHASH; ++pr) { int v = rhk[h]; if (v == rv) { sv = (int)h; break; } if (v == -1) break; h = (h + 1) & (RHASH - 1); } }
        eab[s2] = ((unsigned)su << 16) | (unsigned)(sv & 0xFFFF);
    }
    for (int i = cnt + tid; i < FCAP; i += bs) ek[i] = ~0ull;
    for (int s2 = tid; s2 < RHASH; s2 += bs) {
        ufp[s2] = (short)s2;
        int r = rhk[s2];
        rdt[s2] = (r >= 0) ? dtf[r] : 0.f;
    }
    __syncthreads();

    bitonic4096(ek, tid);   // ascending by (death dt, death pixel, slot)

    // serial Kruskal (elder rule) in LDS
    if (tid == 0) {
        int pc = 0;
        for (int i = 0; i < cnt; ++i) {
            unsigned long long e = ek[i];
            if (e == ~0ull) break;
            int idx = (int)(e & 0xFFFFu);
            int u = (int)((e >> 16) & 0xFFFFu);
            unsigned ab = eab[idx];
            int sa = (int)(ab >> 16), sb = (int)(ab & 0xFFFFu);
            if (sa == 0xFFFF || sb == 0xFFFF) continue;
            while (ufp[sa] != sa) { short g2 = ufp[ufp[sa]]; ufp[sa] = g2; sa = g2; }
            while (ufp[sb] != sb) { short g2 = ufp[ufp[sb]]; ufp[sb] = g2; sb = g2; }
            if (sa == sb) continue;
            float fa = rdt[sa], fb = rdt[sb];
            int elder, young;
            if (fa <= fb) { elder = sa; young = sb; } else { elder = sb; young = sa; }
            ufp[young] = (short)elder;
            float pers = __uint_as_float((unsigned)(e >> 32)) - rdt[young];
            if (pers > 0.f && pc < FCAP - 1) {
                pyd[pc] = ((unsigned)rhk[young] << 16) | (unsigned)u;
                ppr[pc] = pers; ++pc;
            }
        }
        pyd[pc] = ((unsigned)gmin_s << 16) | (unsigned)gmax_s;
        ppr[pc] = gmaxf_s - gminf_s; ++pc;
        pc_s = pc;
    }
    __syncthreads();
    const int pc = pc_s;

    // top-64 by persistence: descending sort via key = (~persbits, idx)
    for (int i = tid; i < FCAP; i += bs) {
        if (i < pc && ppr[i] > 0.f)
            ek[i] = ((unsigned long long)(0xFFFFFFFFu - __float_as_uint(ppr[i])) << 32) | (unsigned)i;
        else ek[i] = ~0ull;
    }
    __syncthreads();
    bitonic4096(ek, tid);
    for (int slot = tid; slot < 64; slot += bs) {
        unsigned long long e = ek[slot];
        int4 o;
        if (e != ~0ull) {
            int i = (int)(e & 0xFFFFFFFFu);
            unsigned pd2 = pyd[i];
            o.x = (int)(pd2 >> 16); o.y = (int)(pd2 & 0xFFFFu); o.z = 1; o.w = 0;
        } else { o.x = 0; o.y = 0; o.z = 0; o.w = 0; }
        sel[f*64 + slot] = o;
    }
}

__global__ __launch_bounds__(64) void k_feat(const float* __restrict__ dt, const int4* __restrict__ sel,
        LayerParams lp, float* __restrict__ x) {
    const int f = blockIdx.x; const int layer = f >> 1, b = f & 1;
    const float* dtf = dt + (size_t)f*NPIX;
    __shared__ float birth[64], death[64], feat[2*TT];
    const int tid = threadIdx.x;
    int4 s = sel[f*64 + tid];
    float bv = dtf[s.x];
    float dv = s.z ? dtf[s.y] : bv;
    birth[tid] = bv; death[tid] = dv;
    __syncthreads();
    if (tid < TT) {
        float t = lp.tseq[layer][tid];
        float m1 = 0.f, m2 = 0.f;
        for (int m = 0; m < 64; ++m) {
            float v = fmaxf(fminf(t - birth[m], death[m] - t), 0.f);
            if (v > m1) { m2 = m1; m1 = v; } else if (v > m2) m2 = v;
        }
        feat[tid] = m1; feat[TT + tid] = m2;
    }
    __syncthreads();
    if (tid < 50) {
        const float* w = lp.gw[layer] + tid * 50;
        float acc = lp.gb[layer][tid];
        #pragma unroll
        for (int j = 0; j < 50; ++j) acc = fmaf(feat[j], w[j], acc);
        x[b*300 + layer*50 + tid] = acc;
    }
}

__global__ __launch_bounds__(512) void k_final(const float* __restrict__ x, const float* __restrict__ fcw,
        const float* __restrict__ fcb, float* __restrict__ out) {
    __shared__ float rl[2][300];
    const int tid = threadIdx.x;
    if (tid < 300) {
        float a0 = x[tid], a1 = x[300 + tid];
        out[14 + tid] = fabsf(a0) + fabsf(a1);
        rl[0][tid] = fmaxf(a0, 0.f);
        rl[1][tid] = fmaxf(a1, 0.f);
    }
    __syncthreads();
    if (tid < 14) {
        int b = tid / 7, i = tid % 7;
        float acc = fcb[i];
        const float* w = fcw + i * 300;
        for (int j = 0; j < 300; ++j) acc = fmaf(rl[b][j], w[j], acc);
        out[b*7 + i] = acc;
    }
}

// ---------------- host ----------------
extern "C" void kernel_launch(void* const* d_in, const int* in_sizes, int n_in,
                              void* d_out, int out_size, void* d_ws, size_t ws_size,
                              hipStream_t stream) {
    (void)in_sizes; (void)n_in; (void)out_size; (void)ws_size;
    const float* inp = (const float*)d_in[0];
    LayerParams lp;
    for (int l = 0; l < 6; ++l) {
        lp.tseq[l] = (const float*)d_in[1 + 3*l];
        lp.gw[l]   = (const float*)d_in[2 + 3*l];
        lp.gb[l]   = (const float*)d_in[3 + 3*l];
    }
    const float* fcw = (const float*)d_in[19];
    const float* fcb = (const float*)d_in[20];

    char* w = (char*)d_ws;
    float* sums = (float*)(w + OFF_SUMS);
    float* p0a = (float*)(w + OFF_P0A);
    float* p1a = (float*)(w + OFF_P1A);
    float* p2a = (float*)(w + OFF_P2A);
    float* p0b = (float*)(w + OFF_P0B);
    float* p1b = (float*)(w + OFF_P1B);
    float* p2b = (float*)(w + OFF_P2B);
    float* dt = (float*)(w + OFF_DT);
    unsigned long long* key = (unsigned long long*)(w + OFF_KEY);
    int* rootd = (int*)(w + OFF_ROOT);
    unsigned long long* hp = (unsigned long long*)(w + OFF_HP);
    unsigned long long* hb = (unsigned long long*)(w + OFF_HB);
    int4* sel = (int4*)(w + OFF_SEL);
    float* xbuf = (float*)(w + OFF_X);

    hipLaunchKernelGGL(k_sums, dim3(6), dim3(256), 0, stream, inp, sums);
    const int prefRows = 6*PW1v + 6*PW2v;
    hipLaunchKernelGGL(k_prefix, dim3(prefRows), dim3(64), 0, stream,
                       inp, p0a, p1a, p2a, p0b, p1b, p2b);
    hipMemsetAsync(hp, 0xFF, (size_t)NFIELD*HSIZE*8, stream);
    hipMemsetAsync(hb, 0xFF, (size_t)NFIELD*HSIZE*8, stream);
    hipLaunchKernelGGL(k_dtm, dim3(8 * 3 * BLKF), dim3(256), 0, stream,
                       sums, p0a, p1a, p2a, p0b, p1b, p2b, dt, key);
    hipLaunchKernelGGL(k_uf, dim3(NFIELD), dim3(1024), 0, stream, key, rootd, hp, hb);
    hipLaunchKernelGGL(k_finish, dim3(NFIELD), dim3(512), 0, stream, dt, key, rootd, hp, hb, sel);
    hipLaunchKernelGGL(k_feat, dim3(NFIELD), dim3(64), 0, stream, dt, sel, lp, xbuf);
    hipLaunchKernelGGL(k_final, dim3(1), dim3(512), 0, stream, xbuf, fcw, fcb, (float*)d_out);
}

// Round 4
// 1113.485 us; speedup vs baseline: 2.4243x; 1.0271x over previous
//
#include <hip/hip_runtime.h>
#include <stdint.h>

#define HWDIM 224
#define NPIX (HWDIM*HWDIM)
#define NFIELD 12
#define TT 25
#define BLKF (NPIX/256)            /* 196 blocks per field */

#define R1v 37
#define PW1v (HWDIM + 2*R1v)        /* 298 */
#define C1v  (PW1v + 1)             /* 299 */
#define R2v 74
#define PW2v (HWDIM + 2*R2v)        /* 372 */
#define C2v  (PW2v + 1)             /* 373 */

#define HSIZE 16384
#define FCAP 4096
#define RHASH 4096

struct LayerParams {
    const float* tseq[6];
    const float* gw[6];
    const float* gb[6];
};

// ---------------- workspace layout ----------------
constexpr size_t alup(size_t x) { return (x + 255) & ~(size_t)255; }
constexpr size_t SZPA = (size_t)6*PW1v*C1v*4;   // one g0 P0 array bytes
constexpr size_t SZPB = (size_t)6*PW2v*C2v*4;   // one g1 P0 array bytes
constexpr size_t OFF_SUMS = 0;
constexpr size_t OFF_P0A = alup(OFF_SUMS + 8*4);
constexpr size_t OFF_PZA = alup(OFF_P0A + SZPA);      // float2 (P1,P2)
constexpr size_t OFF_P0B = alup(OFF_PZA + 2*SZPA);
constexpr size_t OFF_PZB = alup(OFF_P0B + SZPB);
constexpr size_t OFF_DT   = alup(OFF_PZB + 2*SZPB);
constexpr size_t OFF_KEY  = alup(OFF_DT   + (size_t)NFIELD*NPIX*4);
constexpr size_t OFF_ROOT = alup(OFF_KEY  + (size_t)NFIELD*NPIX*8);
constexpr size_t OFF_HP   = alup(OFF_ROOT + (size_t)NFIELD*NPIX*4);
constexpr size_t OFF_HB   = alup(OFF_HP   + (size_t)NFIELD*HSIZE*8);
constexpr size_t OFF_SEL  = alup(OFF_HB   + (size_t)NFIELD*HSIZE*8);
constexpr size_t OFF_X    = alup(OFF_SEL  + (size_t)NFIELD*64*16);

// ---------------- kernels ----------------

__global__ __launch_bounds__(256) void k_sums(const float* __restrict__ inp, float* __restrict__ sums) {
    int img = blockIdx.x; // 0..5 = b*3+c
    const float* p = inp + (size_t)img * NPIX;
    __shared__ float red[256];
    float s = 0.f;
    for (int i = threadIdx.x; i < NPIX; i += 256) s += p[i];
    red[threadIdx.x] = s; __syncthreads();
    for (int w = 128; w > 0; w >>= 1) {
        if (threadIdx.x < w) red[threadIdx.x] += red[threadIdx.x + w];
        __syncthreads();
    }
    if (threadIdx.x == 0) sums[img] = red[0];
}

// One 64-lane wave per padded row. Prefix sums of w, w*x', w*x'^2 (double accum,
// f32 store). P0 dense; (P1,P2) packed as float2 for the weighted pass.
__global__ __launch_bounds__(64) void k_prefix(const float* __restrict__ inp,
        float* __restrict__ p0a, float2* __restrict__ pza,
        float* __restrict__ p0b, float2* __restrict__ pzb) {
    int bidx = blockIdx.x;
    const int tot0 = 6 * PW1v;
    int g = (bidx >= tot0);
    int rem = g ? (bidx - tot0) : bidx;
    const int PW = g ? PW2v : PW1v, R = g ? R2v : R1v, C = PW + 1;
    int img = rem / PW, row = rem % PW;
    float* P0 = (g ? p0b : p0a) + ((size_t)img*PW + row) * C;
    float2* PZ = (g ? pzb : pza) + ((size_t)img*PW + row) * C;
    int iy = row - R;
    bool rowok = ((unsigned)iy < HWDIM);
    const float* src = inp + (size_t)img*NPIX + (size_t)(rowok ? iy : 0)*HWDIM;
    const int lane = threadIdx.x;
    if (lane == 0) { P0[0] = 0.f; PZ[0] = make_float2(0.f, 0.f); }
    double c0 = 0.0, c1 = 0.0, c2 = 0.0;
    for (int i = 0; i < 6; ++i) {
        int k = i*64 + lane;            // element index == xp
        float v = 0.f;
        if (k < PW && rowok) { int ix = k - R; if ((unsigned)ix < HWDIM) v = src[ix]; }
        double xd = (double)k;
        double w0 = v, w1 = v*xd, w2 = v*xd*xd;
        #pragma unroll
        for (int off = 1; off < 64; off <<= 1) {
            double t0 = __shfl_up(w0, off), t1 = __shfl_up(w1, off), t2 = __shfl_up(w2, off);
            if (lane >= off) { w0 += t0; w1 += t1; w2 += t2; }
        }
        if (k < PW) {
            P0[k+1] = (float)(c0 + w0);
            PZ[k+1] = make_float2((float)(c1 + w1), (float)(c2 + w2));
        }
        c0 += __shfl(w0, 63); c1 += __shfl(w1, 63); c2 += __shfl(w2, 63);
    }
}

// XCD-pinned: blockIdx%8 selects the XCD (HW round-robin). XCD 0..5 own one
// g1 field each; XCD 6,7 own three g0 fields each -> per-field prefix arrays
// stay resident in that XCD's 4MB L2.
__global__ __launch_bounds__(256) void k_dtm(const float* __restrict__ sums,
        const float* __restrict__ p0a, const float2* __restrict__ pza,
        const float* __restrict__ p0b, const float2* __restrict__ pzb,
        float* __restrict__ dt, unsigned long long* __restrict__ key) {
    const int xcd = blockIdx.x & 7, slot = blockIdx.x >> 3;
    int f, blk;
    if (xcd < 6) { if (slot >= BLKF) return; f = 6 + xcd; blk = slot; }
    else { if (slot >= 3*BLKF) return; int q = slot / BLKF; f = (xcd - 6)*3 + q; blk = slot - q*BLKF; }
    const int layer = f >> 1, b = f & 1;
    const int g = layer / 3, c = layer % 3;
    const int img = b*3 + c;
    const int R = g ? R2v : R1v, PW = g ? PW2v : PW1v, C = PW + 1;
    const int R2 = 2*R*R;
    const int NTB = R2 + 2;
    __shared__ unsigned char tbl[2*R2v*R2v + 2];
    for (int t = threadIdx.x; t < NTB; t += 256) {
        int k = (int)sqrtf((float)t);
        while ((k+1)*(k+1) <= t) ++k;
        while (k*k > t) --k;
        tbl[t] = (unsigned char)k;
    }
    __syncthreads();
    const float thr = (g ? 0.2f : 0.05f) * sums[img];
    const int p = blk*256 + threadIdx.x;
    const int y = p / HWDIM, x = p % HWDIM;
    const int xc = x + R, yr = y + R;
    const float* __restrict__ P0 = (g ? p0b : p0a) + (size_t)img*PW*C;
    const float2* __restrict__ PZ = (g ? pzb : pza) + (size_t)img*PW*C;
    const int bidx = yr*C + xc;

    // ---- find D = min{X : mass(<=X) >= thr} via secant-seeded exact bracket ----
    int lo = 0, hi = R2 + 1;                 // invariant: mass(<=lo-1) < thr; mass(<=hi) >= thr (hi=R2+1 virtual)
    float Xa = 0.f, ma = 0.f;                // previous eval (virtual (0,0) initially)
    float Xb = -1.f, mb = 0.f;               // last eval
    const int XHAT = g ? 6388 : 1597;        // thr/(rho*pi/2) closed-form seed (density-free)
    for (int it = 0; it < 20; ++it) {
        bool alive = (lo < hi);
        if (__all(!alive)) break;
        int Xp;
        if (it == 0) Xp = XHAT;
        else if (it <= 3) {
            float den = mb - ma;
            float Xs;
            if (fabsf(den) > 1e-20f) Xs = Xa + (thr - ma) * (Xb - Xa) / den;
            else Xs = 0.5f * (float)(lo + hi);
            Xs = fminf(fmaxf(Xs, 0.f), (float)(R2 + 1));
            Xp = (int)Xs;
        } else Xp = (lo + hi) >> 1;
        Xp = min(max(Xp, lo), hi - 1);
        if (!alive) Xp = -1;                 // dead lanes contribute no rows
        // mass(<=Xp)
        float m = 0.f;
        if (Xp >= 0) { int K = min((int)tbl[Xp], R); m = P0[bidx + K + 1] - P0[bidx - K]; }
        int t = Xp - 1;
        int o = C;
        for (int dyy = 1; dyy <= R; ++dyy) {
            if (__all(t < 0)) break;
            if (t >= 0) {
                int K = min((int)tbl[t], R);
                int A = bidx + K + 1, B = bidx - K;
                m += (P0[A - o] - P0[B - o]) + (P0[A + o] - P0[B + o]);
            }
            t -= 2*dyy + 1;
            o += C;
        }
        if (alive) {
            if (m >= thr) hi = Xp; else lo = Xp + 1;
            if (Xb >= 0.f) { Xa = Xb; ma = mb; }
            Xb = (float)Xp; mb = m;
        }
    }
    const int D = lo;
    const bool cross = (D <= R2);
    const int Xin = cross ? (D - 1) : R2;

    // ---- weighted pass at Xin: mass_in and wsum_in ----
    float m_in = 0.f, ws = 0.f;
    const float c2n = -2.f * (float)xc;
    const int xc2i = xc * xc;
    if (Xin >= 0) {
        int K = min((int)tbl[Xin], R);
        int A = bidx + K + 1, B = bidx - K;
        float s0 = P0[A] - P0[B];
        float2 zA = PZ[A], zB = PZ[B];
        m_in += s0;
        ws += fmaf((float)xc2i, s0, fmaf(c2n, zA.x - zB.x, zA.y - zB.y));
    }
    {
        int t = Xin - 1;
        int o = C;
        for (int dyy = 1; dyy <= R; ++dyy) {
            if (__all(t < 0)) break;
            if (t >= 0) {
                int K = min((int)tbl[t], R);
                int A = bidx + K + 1, B = bidx - K;
                float c1 = (float)(dyy*dyy + xc2i);
                {
                    float s0 = P0[A - o] - P0[B - o];
                    float2 zA = PZ[A - o], zB = PZ[B - o];
                    m_in += s0;
                    ws += fmaf(c1, s0, fmaf(c2n, zA.x - zB.x, zA.y - zB.y));
                }
                {
                    float s0 = P0[A + o] - P0[B + o];
                    float2 zA = PZ[A + o], zB = PZ[B + o];
                    m_in += s0;
                    ws += fmaf(c1, s0, fmaf(c2n, zA.x - zB.x, zA.y - zB.y));
                }
            }
            t -= 2*dyy + 1;
            o += C;
        }
    }
    float s = cross ? (ws + (float)D * (thr - m_in)) : ws;
    float dtm2 = s / thr;
    float d = sqrtf(fmaxf(dtm2, 0.f));
    dt[(size_t)f*NPIX + p] = d;
    key[(size_t)f*NPIX + p] = ((unsigned long long)__float_as_uint(d) << 32) | (unsigned)p;
}

__device__ inline unsigned hash64(unsigned long long x) {
    x ^= x >> 33; x *= 0xff51afd7ed558ccdULL;
    x ^= x >> 33; x *= 0xc4ceb9fe1a85ec53ULL;
    x ^= x >> 33;
    return (unsigned)x;
}

// Fused steepest-descent + pointer-jumping (ushort parent in LDS) + inter-basin
// edge extraction. One block per field.
__global__ __launch_bounds__(1024) void k_uf(const unsigned long long* __restrict__ key,
        int* __restrict__ rootd,
        unsigned long long* __restrict__ hpair, unsigned long long* __restrict__ hbest) {
    const int f = blockIdx.x;
    const unsigned long long* kf = key + (size_t)f*NPIX;
    unsigned long long* hp = hpair + (size_t)f*HSIZE;
    unsigned long long* hb = hbest + (size_t)f*HSIZE;
    __shared__ unsigned short par[NPIX];   // 100 KB
    const int tid = threadIdx.x;
    // descent
    for (int p = tid; p < NPIX; p += 1024) {
        unsigned long long best = kf[p]; int bi = p;
        const int y = p / HWDIM, x = p % HWDIM;
        if (y > 0)        { unsigned long long t = kf[p - HWDIM]; if (t < best) { best = t; bi = p - HWDIM; } }
        if (y < HWDIM-1)  { unsigned long long t = kf[p + HWDIM]; if (t < best) { best = t; bi = p + HWDIM; } }
        if (x > 0)        { unsigned long long t = kf[p - 1];     if (t < best) { best = t; bi = p - 1; } }
        if (x < HWDIM-1)  { unsigned long long t = kf[p + 1];     if (t < best) { best = t; bi = p + 1; } }
        par[p] = (unsigned short)bi;
    }
    __syncthreads();
    // pointer jumping in LDS; races are monotone-safe; 2^16 >= NPIX guarantees convergence
    for (int pass = 0; pass < 16; ++pass) {
        for (int p = tid; p < NPIX; p += 1024) par[p] = par[par[p]];
        __syncthreads();
    }
    // edges (right/down) between distinct basins + rootd writeback
    for (int p = tid; p < NPIX; p += 1024) {
        const int rp = par[p];
        rootd[(size_t)f*NPIX + p] = rp;
        const int y = p / HWDIM, x = p % HWDIM;
        const unsigned long long kp = kf[p];
        #pragma unroll
        for (int e = 0; e < 2; ++e) {
            int q;
            if (e == 0) { if (x >= HWDIM-1) continue; q = p + 1; }
            else        { if (y >= HWDIM-1) continue; q = p + HWDIM; }
            int rq = par[q];
            if (rq == rp) continue;
            unsigned long long kq = kf[q];
            unsigned long long ek = (kp > kq) ? kp : kq;      // key of death (later) endpoint
            int ra = min(rp, rq), rb = max(rp, rq);
            unsigned long long pk = ((unsigned long long)(unsigned)ra << 32) | (unsigned)rb;
            unsigned h = hash64(pk) & (HSIZE - 1);
            for (int probe = 0; probe < HSIZE; ++probe) {
                unsigned long long old = atomicCAS(&hp[h], ~0ull, pk);
                if (old == ~0ull || old == pk) { atomicMin(&hb[h], ek); break; }
                h = (h + 1) & (HSIZE - 1);
            }
        }
    }
}

__device__ __forceinline__ void bitonic_n(unsigned long long* ek, int tid, int n) {
    for (int k = 2; k <= n; k <<= 1) {
        for (int j = k >> 1; j > 0; j >>= 1) {
            for (int i = tid; i < n; i += 512) {
                int ixj = i ^ j;
                if (ixj > i) {
                    unsigned long long a = ek[i], b = ek[ixj];
                    if (((i & k) == 0) ? (a > b) : (a < b)) { ek[i] = b; ek[ixj] = a; }
                }
            }
            __syncthreads();
        }
    }
}

__global__ __launch_bounds__(512) void k_finish(const float* __restrict__ dt, const unsigned long long* __restrict__ key,
        const int* __restrict__ rootd,
        const unsigned long long* __restrict__ hpair, const unsigned long long* __restrict__ hbest,
        int4* __restrict__ sel) {
    const int f = blockIdx.x;
    const int tid = threadIdx.x; const int bs = 512;
    const float* dtf = dt + (size_t)f*NPIX;
    const unsigned long long* kf = key + (size_t)f*NPIX;
    const int* rf = rootd + (size_t)f*NPIX;
    const unsigned long long* hp = hpair + (size_t)f*HSIZE;
    const unsigned long long* hb = hbest + (size_t)f*HSIZE;

    __shared__ unsigned long long ek[FCAP];   // 32KB sort keys
    __shared__ unsigned int epk[FCAP];        // 16KB (ra<<16)|rb
    __shared__ unsigned int eab[FCAP];        // 16KB (slot_ru<<16)|slot_rv
    __shared__ int rhk[RHASH];                // 16KB root-pixel hash keys (-1 empty)
    __shared__ short ufp[RHASH];              // 8KB  union-find parent (slot)
    __shared__ float rdt[RHASH];              // 16KB dt at root
    __shared__ unsigned int pyd[FCAP];        // 16KB (young<<16)|death
    __shared__ float ppr[FCAP];               // 16KB persistence
    __shared__ unsigned long long redk[512];
    __shared__ float redf[512];
    __shared__ int redi[512];
    __shared__ int cnt_s, pc_s;
    __shared__ int gmin_s, gmax_s; __shared__ float gminf_s, gmaxf_s;

    for (int i = tid; i < RHASH; i += bs) rhk[i] = -1;
    if (tid == 0) { cnt_s = 0; pc_s = 0; }

    // global min/max over key
    unsigned long long mymin = ~0ull;
    float bf = -1.f; int bi = 0x7fffffff;
    for (int p = tid; p < NPIX; p += bs) {
        unsigned long long kk = kf[p];
        if (kk < mymin) mymin = kk;
        float v = __uint_as_float((unsigned)(kk >> 32));
        if (v > bf || (v == bf && p < bi)) { bf = v; bi = p; }
    }
    redk[tid] = mymin; redf[tid] = bf; redi[tid] = bi;
    __syncthreads();
    for (int w = 256; w > 0; w >>= 1) {
        if (tid < w) {
            if (redk[tid + w] < redk[tid]) redk[tid] = redk[tid + w];
            float vf = redf[tid + w]; int vi = redi[tid + w];
            if (vf > redf[tid] || (vf == redf[tid] && vi < redi[tid])) { redf[tid] = vf; redi[tid] = vi; }
        }
        __syncthreads();
    }
    if (tid == 0) {
        gmin_s = (int)(unsigned)redk[0];
        gminf_s = __uint_as_float((unsigned)(redk[0] >> 32));
        gmax_s = redi[0]; gmaxf_s = redf[0];
    }
    __syncthreads();

    // Phase A: compact hash table into LDS + insert roots into dense hash
    for (int i = tid; i < HSIZE; i += bs) {
        unsigned long long pk = hp[i];
        if (pk != ~0ull) {
            int slot = atomicAdd(&cnt_s, 1);
            if (slot < FCAP) {
                unsigned long long e = hb[i];
                unsigned u = (unsigned)e & 0xFFFFu;  // death pixel (< 65536)
                ek[slot] = (e & 0xFFFFFFFF00000000ull) | ((unsigned long long)u << 16) | (unsigned)slot;
                int ra = (int)(pk >> 32), rb = (int)(pk & 0xFFFFFFFFu);
                epk[slot] = ((unsigned)ra << 16) | (unsigned)rb;
                #pragma unroll
                for (int pass = 0; pass < 2; ++pass) {
                    int r = pass ? rb : ra;
                    unsigned h = ((unsigned)r * 2654435761u) & (RHASH - 1);
                    for (int pr = 0; pr < RHASH; ++pr) {
                        int old = atomicCAS(&rhk[h], -1, r);
                        if (old == -1 || old == r) break;
                        h = (h + 1) & (RHASH - 1);
                    }
                }
            }
        }
    }
    __syncthreads();
    int cnt = min(cnt_s, FCAP);
    int n1 = 64; while (n1 < cnt) n1 <<= 1;
    // Phase B (parallel): resolve per-edge (slot_ru, slot_rv)
    for (int s2 = tid; s2 < cnt; s2 += bs) {
        int u = (int)((ek[s2] >> 16) & 0xFFFFu);
        unsigned pk2 = epk[s2];
        int ra = (int)(pk2 >> 16), rb = (int)(pk2 & 0xFFFFu);
        int ru = rf[u];
        int rv = (ru == ra) ? rb : ra;
        int su = -1, sv = -1;
        { unsigned h = ((unsigned)ru * 2654435761u) & (RHASH - 1);
          for (int pr = 0; pr < RHASH; ++pr) { int v = rhk[h]; if (v == ru) { su = (int)h; break; } if (v == -1) break; h = (h + 1) & (RHASH - 1); } }
        { unsigned h = ((unsigned)rv * 2654435761u) & (RHASH - 1);
          for (int pr = 0; pr < RHASH; ++pr) { int v = rhk[h]; if (v == rv) { sv = (int)h; break; } if (v == -1) break; h = (h + 1) & (RHASH - 1); } }
        eab[s2] = ((unsigned)su << 16) | (unsigned)(sv & 0xFFFF);
    }
    for (int i = cnt + tid; i < n1; i += bs) ek[i] = ~0ull;
    for (int s2 = tid; s2 < RHASH; s2 += bs) {
        ufp[s2] = (short)s2;
        int r = rhk[s2];
        rdt[s2] = (r >= 0) ? dtf[r] : 0.f;
    }
    __syncthreads();

    bitonic_n(ek, tid, n1);   // ascending by (death dt, death pixel, slot)

    // serial Kruskal (elder rule) in LDS
    if (tid == 0) {
        int pc = 0;
        for (int i = 0; i < cnt; ++i) {
            unsigned long long e = ek[i];
            if (e == ~0ull) break;
            int idx = (int)(e & 0xFFFFu);
            int u = (int)((e >> 16) & 0xFFFFu);
            unsigned ab = eab[idx];
            int sa = (int)(ab >> 16), sb = (int)(ab & 0xFFFFu);
            if (sa == 0xFFFF || sb == 0xFFFF) continue;
            while (ufp[sa] != sa) { short g2 = ufp[ufp[sa]]; ufp[sa] = g2; sa = g2; }
            while (ufp[sb] != sb) { short g2 = ufp[ufp[sb]]; ufp[sb] = g2; sb = g2; }
            if (sa == sb) continue;
            float fa = rdt[sa], fb = rdt[sb];
            int elder, young;
            if (fa <= fb) { elder = sa; young = sb; } else { elder = sb; young = sa; }
            ufp[young] = (short)elder;
            float pers = __uint_as_float((unsigned)(e >> 32)) - rdt[young];
            if (pers > 0.f && pc < FCAP - 1) {
                pyd[pc] = ((unsigned)rhk[young] << 16) | (unsigned)u;
                ppr[pc] = pers; ++pc;
            }
        }
        pyd[pc] = ((unsigned)gmin_s << 16) | (unsigned)gmax_s;
        ppr[pc] = gmaxf_s - gminf_s; ++pc;
        pc_s = pc;
    }
    __syncthreads();
    const int pc = pc_s;
    int n2 = 64; while (n2 < pc) n2 <<= 1;

    // top-64 by persistence: descending sort via key = (~persbits, idx)
    for (int i = tid; i < n2; i += bs) {
        if (i < pc && ppr[i] > 0.f)
            ek[i] = ((unsigned long long)(0xFFFFFFFFu - __float_as_uint(ppr[i])) << 32) | (unsigned)i;
        else ek[i] = ~0ull;
    }
    __syncthreads();
    bitonic_n(ek, tid, n2);
    for (int slot = tid; slot < 64; slot += bs) {
        unsigned long long e = ek[slot];
        int4 o;
        if (e != ~0ull) {
            int i = (int)(e & 0xFFFFFFFFu);
            unsigned pd2 = pyd[i];
            o.x = (int)(pd2 >> 16); o.y = (int)(pd2 & 0xFFFFu); o.z = 1; o.w = 0;
        } else { o.x = 0; o.y = 0; o.z = 0; o.w = 0; }
        sel[f*64 + slot] = o;
    }
}

__global__ __launch_bounds__(64) void k_feat(const float* __restrict__ dt, const int4* __restrict__ sel,
        LayerParams lp, float* __restrict__ x) {
    const int f = blockIdx.x; const int layer = f >> 1, b = f & 1;
    const float* dtf = dt + (size_t)f*NPIX;
    __shared__ float birth[64], death[64], feat[2*TT];
    const int tid = threadIdx.x;
    int4 s = sel[f*64 + tid];
    float bv = dtf[s.x];
    float dv = s.z ? dtf[s.y] : bv;
    birth[tid] = bv; death[tid] = dv;
    __syncthreads();
    if (tid < TT) {
        float t = lp.tseq[layer][tid];
        float m1 = 0.f, m2 = 0.f;
        for (int m = 0; m < 64; ++m) {
            float v = fmaxf(fminf(t - birth[m], death[m] - t), 0.f);
            if (v > m1) { m2 = m1; m1 = v; } else if (v > m2) m2 = v;
        }
        feat[tid] = m1; feat[TT + tid] = m2;
    }
    __syncthreads();
    if (tid < 50) {
        const float* w = lp.gw[layer] + tid * 50;
        float acc = lp.gb[layer][tid];
        #pragma unroll
        for (int j = 0; j < 50; ++j) acc = fmaf(feat[j], w[j], acc);
        x[b*300 + layer*50 + tid] = acc;
    }
}

__global__ __launch_bounds__(512) void k_final(const float* __restrict__ x, const float* __restrict__ fcw,
        const float* __restrict__ fcb, float* __restrict__ out) {
    __shared__ float rl[2][300];
    const int tid = threadIdx.x;
    if (tid < 300) {
        float a0 = x[tid], a1 = x[300 + tid];
        out[14 + tid] = fabsf(a0) + fabsf(a1);
        rl[0][tid] = fmaxf(a0, 0.f);
        rl[1][tid] = fmaxf(a1, 0.f);
    }
    __syncthreads();
    if (tid < 14) {
        int b = tid / 7, i = tid % 7;
        float acc = fcb[i];
        const float* w = fcw + i * 300;
        for (int j = 0; j < 300; ++j) acc = fmaf(rl[b][j], w[j], acc);
        out[b*7 + i] = acc;
    }
}

// ---------------- host ----------------
extern "C" void kernel_launch(void* const* d_in, const int* in_sizes, int n_in,
                              void* d_out, int out_size, void* d_ws, size_t ws_size,
                              hipStream_t stream) {
    (void)in_sizes; (void)n_in; (void)out_size; (void)ws_size;
    const float* inp = (const float*)d_in[0];
    LayerParams lp;
    for (int l = 0; l < 6; ++l) {
        lp.tseq[l] = (const float*)d_in[1 + 3*l];
        lp.gw[l]   = (const float*)d_in[2 + 3*l];
        lp.gb[l]   = (const float*)d_in[3 + 3*l];
    }
    const float* fcw = (const float*)d_in[19];
    const float* fcb = (const float*)d_in[20];

    char* w = (char*)d_ws;
    float* sums = (float*)(w + OFF_SUMS);
    float* p0a = (float*)(w + OFF_P0A);
    float2* pza = (float2*)(w + OFF_PZA);
    float* p0b = (float*)(w + OFF_P0B);
    float2* pzb = (float2*)(w + OFF_PZB);
    float* dt = (float*)(w + OFF_DT);
    unsigned long long* key = (unsigned long long*)(w + OFF_KEY);
    int* rootd = (int*)(w + OFF_ROOT);
    unsigned long long* hp = (unsigned long long*)(w + OFF_HP);
    unsigned long long* hb = (unsigned long long*)(w + OFF_HB);
    int4* sel = (int4*)(w + OFF_SEL);
    float* xbuf = (float*)(w + OFF_X);

    hipLaunchKernelGGL(k_sums, dim3(6), dim3(256), 0, stream, inp, sums);
    const int prefRows = 6*PW1v + 6*PW2v;
    hipLaunchKernelGGL(k_prefix, dim3(prefRows), dim3(64), 0, stream,
                       inp, p0a, pza, p0b, pzb);
    hipMemsetAsync(hp, 0xFF, (size_t)NFIELD*HSIZE*8, stream);
    hipMemsetAsync(hb, 0xFF, (size_t)NFIELD*HSIZE*8, stream);
    hipLaunchKernelGGL(k_dtm, dim3(8 * 3 * BLKF), dim3(256), 0, stream,
                       sums, p0a, pza, p0b, pzb, dt, key);
    hipLaunchKernelGGL(k_uf, dim3(NFIELD), dim3(1024), 0, stream, key, rootd, hp, hb);
    hipLaunchKernelGGL(k_finish, dim3(NFIELD), dim3(512), 0, stream, dt, key, rootd, hp, hb, sel);
    hipLaunchKernelGGL(k_feat, dim3(NFIELD), dim3(64), 0, stream, dt, sel, lp, xbuf);
    hipLaunchKernelGGL(k_final, dim3(1), dim3(512), 0, stream, xbuf, fcw, fcb, (float*)d_out);
}